// Round 15
// baseline (133.563 us; speedup 1.0000x reference)
//
#include <hip/hip_runtime.h>
#include <cstdint>
#include <cstddef>

#define D_DIM 320
#define NEGINF (-1e30f)

typedef __attribute__((ext_vector_type(8))) short bf16x8_t;
typedef __attribute__((ext_vector_type(4))) float f32x4_t;
typedef __attribute__((ext_vector_type(16))) float f32x16_t;

struct Tab {
  int T[11], S[11], zoff[11], wsoff[11];
  int tileStart[12], instStart[12], rstart[12];
  float scale[11];
  int totTemp, totInst, totr;
};

__device__ __forceinline__ float bf2f(unsigned short u) {
  union { unsigned int i; float f; } v; v.i = ((unsigned int)u) << 16; return v.f;
}
__device__ __forceinline__ unsigned short f2bf(float f) {
  union { float f; unsigned int i; } u; u.f = f;
  unsigned int b = u.i + 0x7FFFu + ((u.i >> 16) & 1u);
  return (unsigned short)(b >> 16);
}

__device__ __forceinline__ const unsigned short* zrowb(
    const unsigned short* __restrict__ z1, const unsigned short* __restrict__ z2,
    int b, int T, int r) {
  return (r < T) ? (z1 + ((size_t)b * T + r) * D_DIM)
                 : (z2 + ((size_t)b * T + (r - T)) * D_DIM);
}

#define GLOAD_LDS16(SRC, DST)                                                   \
  __builtin_amdgcn_global_load_lds(                                             \
      (const __attribute__((address_space(1))) void*)(SRC),                     \
      (__attribute__((address_space(3))) void*)(DST), 16, 0, 0)

// ---- ring-3 tile-engine macros: buffers at short-offsets 0/8192/16384 ----
#define BUF1 8192
#define BUF2 16384

#define STAGE(koff, bufofs)                                                     \
    do {                                                                        \
      GLOAD_LDS16(gA0 + (koff), dA0 + (bufofs));                                \
      GLOAD_LDS16(gA1 + (koff), dA1 + (bufofs));                                \
      GLOAD_LDS16(gB0 + (koff), dB0 + (bufofs));                                \
      GLOAD_LDS16(gB1 + (koff), dB1 + (bufofs));                                \
    } while (0)

#define PHASE3(k, bo, bo2, VM, DO_PF)                                           \
    do {                                                                        \
      asm volatile("s_waitcnt vmcnt(" #VM ")" ::: "memory");                    \
      __builtin_amdgcn_s_barrier();                                             \
      if (DO_PF) STAGE((k + 2) * 32, bo2);                                      \
      bf16x8_t af[4], bfr[4];                                                   \
      _Pragma("unroll")                                                         \
      for (int at = 0; at < 4; ++at)                                            \
        af[at] = *(const bf16x8_t*)(vA + (bo) + at * 128);                      \
      _Pragma("unroll")                                                         \
      for (int ct = 0; ct < 4; ++ct)                                            \
        bfr[ct] = *(const bf16x8_t*)(vB + (bo) + ct * 128);                     \
      asm volatile("s_waitcnt lgkmcnt(0)" ::: "memory");                        \
      __builtin_amdgcn_sched_barrier(0);                                        \
      __builtin_amdgcn_s_setprio(1);                                            \
      _Pragma("unroll")                                                         \
      for (int ct = 0; ct < 4; ++ct)                                            \
        _Pragma("unroll")                                                       \
        for (int at = 0; at < 4; ++at)                                          \
          acc[at][ct] = __builtin_amdgcn_mfma_f32_16x16x32_bf16(                \
              af[at], bfr[ct], acc[at][ct], 0, 0, 0);                           \
      __builtin_amdgcn_s_setprio(0);                                            \
    } while (0)

// ================= shared device helpers =================
// full 128x128 temporal tile body — R13-proven per-row two-pass LSE epilogue
__device__ __forceinline__ void tile_body(
    unsigned char* smem, int tid,
    const unsigned short* zz1, const unsigned short* zz2,
    int b, int T, int S, int rb, int sg,
    float* wm, float* wv) {
  int N = 2 * T;
  int row0 = rb * 128, col0 = sg * 128;
  int w = tid >> 6, lane = tid & 63;
  int lq = lane >> 4, lr = lane & 15;
  int wr = w >> 1, wc = w & 1;

  unsigned short* lds = (unsigned short*)smem;

  int ra0 = row0 + lane;        if (ra0 > N - 1) ra0 = N - 1;
  int ra1 = row0 + 64 + lane;   if (ra1 > N - 1) ra1 = N - 1;
  int ca0 = col0 + lane;        if (ca0 > N - 1) ca0 = N - 1;
  int ca1 = col0 + 64 + lane;   if (ca1 > N - 1) ca1 = N - 1;
  const unsigned short* gA0 = zrowb(zz1, zz2, b, T, ra0) + w * 8;
  const unsigned short* gA1 = zrowb(zz1, zz2, b, T, ra1) + w * 8;
  const unsigned short* gB0 = zrowb(zz1, zz2, b, T, ca0) + w * 8;
  const unsigned short* gB1 = zrowb(zz1, zz2, b, T, ca1) + w * 8;
  unsigned short* dA0 = &lds[((w) * 128 + lane) * 8];
  unsigned short* dA1 = &lds[((w) * 128 + 64 + lane) * 8];
  unsigned short* dB0 = &lds[((4 + w) * 128 + lane) * 8];
  unsigned short* dB1 = &lds[((4 + w) * 128 + 64 + lane) * 8];

  f32x4_t acc[4][4];
#pragma unroll
  for (int at = 0; at < 4; ++at)
#pragma unroll
    for (int ct = 0; ct < 4; ++ct) acc[at][ct] = (f32x4_t)(0.f);

  const unsigned short* vA = &lds[((lq) * 128 + wr * 64 + lr) * 8];
  const unsigned short* vB = &lds[((4 + lq) * 128 + wc * 64 + lr) * 8];

  STAGE(0, 0);
  STAGE(32, BUF1);
  PHASE3(0, 0,    BUF2, 4, 1);
  PHASE3(1, BUF1, 0,    4, 1);
  PHASE3(2, BUF2, BUF1, 4, 1);
  PHASE3(3, 0,    BUF2, 4, 1);
  PHASE3(4, BUF1, 0,    4, 1);
  PHASE3(5, BUF2, BUF1, 4, 1);
  PHASE3(6, 0,    BUF2, 4, 1);
  PHASE3(7, BUF1, 0,    4, 1);
  PHASE3(8, BUF2, 0,    4, 0);
  PHASE3(9, 0,    0,    0, 0);
  __builtin_amdgcn_s_barrier();  // staging dead; alias epilogue into buffer0

  float (*mS)[128] = (float(*)[128])(smem);
  float (*sS)[128] = (float(*)[128])(smem + 1024);
  float (*mC)[128] = (float(*)[128])(smem + 2048);
  float (*sC)[128] = (float(*)[128])(smem + 3072);

  // row-LSE -> partial (col-seg sg)
#pragma unroll
  for (int at = 0; at < 4; ++at) {
#pragma unroll
    for (int rg = 0; rg < 4; ++rg) {
      int rloc = wr * 64 + at * 16 + lq * 4 + rg;
      int rglob = row0 + rloc;
      float v[4];
#pragma unroll
      for (int ct = 0; ct < 4; ++ct) {
        int cg = col0 + wc * 64 + ct * 16 + lr;
        v[ct] = (cg < N && cg != rglob) ? acc[at][ct][rg] : NEGINF;
      }
      float m = fmaxf(fmaxf(v[0], v[1]), fmaxf(v[2], v[3]));
#pragma unroll
      for (int o = 1; o < 16; o <<= 1) m = fmaxf(m, __shfl_xor(m, o));
      float sv = __expf(v[0] - m) + __expf(v[1] - m) +
                 __expf(v[2] - m) + __expf(v[3] - m);
#pragma unroll
      for (int o = 1; o < 16; o <<= 1) sv += __shfl_xor(sv, o);
      if (lr == 0) { mS[wc][rloc] = m; sS[wc][rloc] = sv; }
    }
  }
  // col-LSE (symmetry) -> partial (col-seg rb); off-diag tiles only
  if (rb != sg) {
#pragma unroll
    for (int ct = 0; ct < 4; ++ct) {
      float m = NEGINF;
#pragma unroll
      for (int at = 0; at < 4; ++at)
#pragma unroll
        for (int rg = 0; rg < 4; ++rg) m = fmaxf(m, acc[at][ct][rg]);
      m = fmaxf(m, __shfl_xor(m, 16));
      m = fmaxf(m, __shfl_xor(m, 32));
      float s = 0.f;
#pragma unroll
      for (int at = 0; at < 4; ++at)
#pragma unroll
        for (int rg = 0; rg < 4; ++rg) s += __expf(acc[at][ct][rg] - m);
      s += __shfl_xor(s, 16);
      s += __shfl_xor(s, 32);
      if (lq == 0) {
        mC[wr][wc * 64 + ct * 16 + lr] = m;
        sC[wr][wc * 64 + ct * 16 + lr] = s;
      }
    }
  }
  __syncthreads();

  if (tid < 128) {
    int rglob = row0 + tid;
    if (rglob < N) {
      float m0 = mS[0][tid], m1 = mS[1][tid];
      float m = fmaxf(m0, m1);
      float sv = sS[0][tid] * __expf(m0 - m) + sS[1][tid] * __expf(m1 - m);
      int idx = (b * S + sg) * N + rglob;
      wm[idx] = m;
      wv[idx] = sv;
    }
    if (rb != sg) {
      float m0 = mC[0][tid], m1 = mC[1][tid];
      float m = fmaxf(m0, m1);
      float sv = sC[0][tid] * __expf(m0 - m) + sC[1][tid] * __expf(m1 - m);
      int idx = (b * S + rb) * N + col0 + tid;
      wm[idx] = m;
      wv[idx] = sv;
    }
  }
}

// instance (16x16, one wave per t): returns wave loss sum (valid at lane 0)
__device__ __forceinline__ float inst_wave(
    const unsigned short* zz1, const unsigned short* zz2, int T, int t, int lane) {
  int lq = lane >> 4, lr = lane & 15;
  const unsigned short* zr = (lr < 8)
      ? zz1 + ((size_t)lr * T + t) * D_DIM
      : zz2 + ((size_t)(lr - 8) * T + t) * D_DIM;
  zr += lq * 8;
  f32x4_t c = (f32x4_t)(0.f);
#pragma unroll
  for (int k = 0; k < 10; ++k) {
    bf16x8_t a = *(const bf16x8_t*)(zr + k * 32);
    c = __builtin_amdgcn_mfma_f32_16x16x32_bf16(a, a, c, 0, 0, 0);
  }
  float lsum = 0.f;
#pragma unroll
  for (int rg = 0; rg < 4; ++rg) {
    int rrow = lq * 4 + rg;
    float v = c[rg];
    float x = (lr != rrow) ? v : NEGINF;
    float m = x;
#pragma unroll
    for (int o = 1; o < 16; o <<= 1) m = fmaxf(m, __shfl_xor(m, o));
    float s = __expf(x - m);
#pragma unroll
    for (int o = 1; o < 16; o <<= 1) s += __shfl_xor(s, o);
    int pos = (rrow < 8) ? rrow + 8 : rrow - 8;
    if (lr == pos) lsum += m + __logf(s) - v;
  }
#pragma unroll
  for (int o = 1; o < 64; o <<= 1) lsum += __shfl_xor(lsum, o);
  return lsum;
}

// ---------------- L1: [8 sort blocks] + [convert blocks] ----------------
__global__ __launch_bounds__(256) void l1_kernel(
    const int* __restrict__ time0,
    const float* __restrict__ i1, const float* __restrict__ i2,
    unsigned short* __restrict__ o1, unsigned short* __restrict__ o2,
    int n4, float* __restrict__ out, int outn, int nconv,
    int* __restrict__ SET0, int* __restrict__ L0LEN,
    int* __restrict__ SET5, int* __restrict__ L5LEN) {
  __shared__ __align__(16) unsigned char smem[43264];
  int bx = blockIdx.x;
  int tid = threadIdx.x;

  if (bx < 8) {
    // ===== bucket-rank stable argsort + origin-set expansion =====
    int b = bx;
    int lane = tid & 63, wid = tid >> 6;
    int* tcur = (int*)smem;
    unsigned* hist = (unsigned*)(smem + 4096);
    unsigned* cum = (unsigned*)(smem + 8192);
    unsigned long long* arr = (unsigned long long*)(smem + 12288);
    int* sortedIdx = (int*)(smem + 20480);
    int* tnew = (int*)(smem + 24576);
    int* srcK = (int*)(smem + 26624);
    int* setA = (int*)(smem + 28672);
    int* setB = (int*)(smem + 32768);
    int* lenA = (int*)(smem + 36864);
    int* lenB = (int*)(smem + 40960);
    unsigned* minW = (unsigned*)(smem + 43008);
    unsigned* maxW = (unsigned*)(smem + 43072);
    unsigned* wsum = (unsigned*)(smem + 43136);
    int* wcnt = (int*)(smem + 43200);

#pragma unroll
    for (int i = 0; i < 4; ++i) {
      int e = tid + 256 * i;
      tcur[e] = time0[b * 1024 + e];
      setA[e] = e;
      lenA[e] = 1;
    }
    __syncthreads();

    int pp = 0;
    for (int lvl = 1; lvl <= 10; ++lvl) {
      int T = 2048 >> lvl;
      int n = T - 1, half = T >> 1;
      bool act[4];
      int dd[4];
      unsigned bkey[4];
      unsigned mn = 0xFFFFFFFFu, mx = 0u;
#pragma unroll
      for (int i = 0; i < 4; ++i) {
        int e = tid + 256 * i;
        act[i] = e < n;
        dd[i] = 0; bkey[i] = 0;
        if (act[i]) {
          dd[i] = tcur[e + 1] - tcur[e];
          bkey[i] = __float_as_uint((float)dd[i]);
          mn = mn < bkey[i] ? mn : bkey[i];
          mx = mx > bkey[i] ? mx : bkey[i];
        }
        hist[e] = 0;
      }
#pragma unroll
      for (int o = 1; o < 64; o <<= 1) {
        unsigned m2 = (unsigned)__shfl_xor((int)mn, o);
        unsigned x2 = (unsigned)__shfl_xor((int)mx, o);
        mn = mn < m2 ? mn : m2;
        mx = mx > x2 ? mx : x2;
      }
      if (lane == 0) { minW[wid] = mn; maxW[wid] = mx; }
      __syncthreads();

      unsigned bmin = 0xFFFFFFFFu, bmax = 0;
#pragma unroll
      for (int i = 0; i < 4; ++i) {
        bmin = bmin < minW[i] ? bmin : minW[i];
        bmax = bmax > maxW[i] ? bmax : maxW[i];
      }
      unsigned long long range = (unsigned long long)(bmax - bmin) + 1;
      unsigned long long scl = (1024ULL << 30) / range;
      int bkt[4]; unsigned av[4];
#pragma unroll
      for (int i = 0; i < 4; ++i) {
        if (act[i]) {
          int bk = (int)(((unsigned long long)(bkey[i] - bmin) * scl) >> 30);
          bkt[i] = bk > 1023 ? 1023 : bk;
          av[i] = atomicAdd(&hist[bkt[i]], 1u);
        }
      }
      __syncthreads();

      {  // exclusive scan over 1024 bins: 4 bins/thread
        unsigned l0 = hist[4 * tid], l1 = hist[4 * tid + 1],
                 l2 = hist[4 * tid + 2], l3 = hist[4 * tid + 3];
        unsigned s = l0 + l1 + l2 + l3;
        unsigned inc = s;
#pragma unroll
        for (int o = 1; o < 64; o <<= 1) {
          unsigned t = (unsigned)__shfl_up((int)inc, o);
          if (lane >= o) inc += t;
        }
        if (lane == 63) wsum[wid] = inc;
        __syncthreads();
        unsigned wpre = 0;
        for (int j = 0; j < wid; ++j) wpre += wsum[j];
        unsigned ex = wpre + inc - s;
        cum[4 * tid] = ex;
        cum[4 * tid + 1] = ex + l0;
        cum[4 * tid + 2] = ex + l0 + l1;
        cum[4 * tid + 3] = ex + l0 + l1 + l2;
      }
      __syncthreads();

      unsigned long long key[4];
#pragma unroll
      for (int i = 0; i < 4; ++i) {
        if (act[i]) {
          key[i] = ((unsigned long long)(unsigned)dd[i] << 10) |
                   (unsigned)(tid + 256 * i);
          arr[cum[bkt[i]] + av[i]] = key[i];
        }
      }
      __syncthreads();

#pragma unroll
      for (int i = 0; i < 4; ++i) {
        if (act[i]) {
          int base = (int)cum[bkt[i]];
          int occ = (int)hist[bkt[i]];
          int c = 0;
          for (int j = 0; j < occ; ++j) c += (arr[base + j] < key[i]) ? 1 : 0;
          sortedIdx[base + c] = tid + 256 * i;
        }
      }
      __syncthreads();

      bool msk[4]; int rw[4];
#pragma unroll
      for (int i = 0; i < 4; ++i) {
        int k = tid + 256 * i;
        msk[i] = (k < n) && (sortedIdx[k] < half);
        unsigned long long bal = __ballot(msk[i]);
        rw[i] = __popcll(bal & ((1ull << lane) - 1ull));
        if (lane == 0) wcnt[i * 4 + wid] = (int)__popcll(bal);
      }
      __syncthreads();
#pragma unroll
      for (int i = 0; i < 4; ++i) {
        if (msk[i]) {
          int seg = i * 4 + wid;
          int pre = 0;
          for (int j = 0; j < seg; ++j) pre += wcnt[j];
          int rr = pre + rw[i];
          int k = tid + 256 * i;
          srcK[rr] = k;
          tnew[rr] = (tcur[k] + tcur[k + 1]) >> 1;
        }
      }
      __syncthreads();

      if (lvl == 6) {
        int* sp = pp ? setB : setA;
        int* lp = pp ? lenB : lenA;
        if (tid < 32) { sp[tid] = tid; lp[tid] = 1; }
        __syncthreads();
      }
      {
        int ll = (lvl <= 5) ? lvl : (lvl - 5);
        int* sp = pp ? setB : setA;
        int* lp = pp ? lenB : lenA;
        int* sc = pp ? setA : setB;
        int* lc = pp ? lenA : lenB;
        int *gset, *glen;
        if (lvl <= 5) {
          gset = SET0 + b * 5120 + (lvl - 1) * 1024;
          glen = L0LEN + b * 992 + (1024 - (1024 >> (lvl - 1)));
        } else {
          gset = SET5 + b * 160 + (lvl - 6) * 32;
          glen = L5LEN + b * 32 + (32 - (32 >> (lvl - 6)));
        }
        int tmax = half << ll;
#pragma unroll
        for (int i = 0; i < 4; ++i) {
          int s = tid + 256 * i;
          if (s < tmax) {
            int j = s >> ll, e2 = s & ((1 << ll) - 1);
            int k = srcK[j];
            int la = lp[k], lb2 = lp[k + 1];
            int v = -1;
            int sh = ll - 1;
            if (e2 < la) v = sp[(k << sh) + e2];
            else if (e2 < la + lb2) v = sp[((k + 1) << sh) + (e2 - la)];
            if (e2 == 0) { lc[j] = la + lb2; glen[j] = la + lb2; }
            if (v >= 0) { sc[s] = v; gset[s] = v; }
          }
        }
        __syncthreads();
        pp ^= 1;
      }
#pragma unroll
      for (int i = 0; i < 4; ++i) {
        int j = tid + 256 * i;
        if (j < half) tcur[j] = tnew[j];
      }
      __syncthreads();
    }
  } else {
    // ---------- fp32 -> bf16 convert (both arrays) + zero out ----------
    int i = (bx - 8) * 256 + tid;
    if (i < outn) out[i] = 0.f;
    int stride = nconv * 256;
    for (int j = i; j < n4; j += stride) {
      float4 v = ((const float4*)i1)[j];
      ushort4 r;
      r.x = f2bf(v.x); r.y = f2bf(v.y); r.z = f2bf(v.z); r.w = f2bf(v.w);
      ((ushort4*)o1)[j] = r;
      float4 u = ((const float4*)i2)[j];
      ushort4 q;
      q.x = f2bf(u.x); q.y = f2bf(u.y); q.z = f2bf(u.z); q.w = f2bf(u.w);
      ((ushort4*)o2)[j] = q;
    }
  }
}

// ---------------- L2: [1088 L0 tiles] + [256 L0 inst] + [2480 mat1] ----------
__global__ __launch_bounds__(256, 3) void l2_kernel(
    unsigned short* __restrict__ z1, unsigned short* __restrict__ z2,
    float* __restrict__ wsm, float* __restrict__ wss,
    float* __restrict__ wsInst,
    const int* __restrict__ SET0, const int* __restrict__ L0LEN) {
  __shared__ __align__(16) unsigned char smem[49152];
  int bx = blockIdx.x;
  int tid = threadIdx.x;

  if (bx < 1088) {
    // ========== level-0 temporal tile (rb<=sg) ==========
    const int T = 1024, S = 16;
    int b = bx % 8;
    int pr = bx / 8;
    int rb = 0, tt = pr;
    while (tt >= S - rb) { tt -= S - rb; ++rb; }
    int sg = rb + tt;
    tile_body(smem, tid, z1, z2, b, T, S, rb, sg, wsm, wss);
  } else if (bx < 1344) {
    // ========== level-0 instance: one wave per t ==========
    int iw = (bx - 1088) * 4 + (tid >> 6);
    float lsum = inst_wave(z1, z2, 1024, iw, tid & 63);
    if ((tid & 63) == 0) wsInst[iw] = lsum * (1.0f / 360448.0f);
  } else {
    // ========== mat1: z levels 1..5 = max over level-0 origin sets ==========
    int g = (bx - 1344) * 256 + tid;
    int c = g % 40;
    int t2 = g / 40;
    int rr = t2 % 992;
    int bzi = t2 / 992;
    int b = bzi & 7;
    unsigned short* z = (bzi >> 3) ? z2 : z1;
    int l, j, off0;
    if (rr < 512)      { l = 1; j = rr;       off0 = 0; }
    else if (rr < 768) { l = 2; j = rr - 512; off0 = 512; }
    else if (rr < 896) { l = 3; j = rr - 768; off0 = 768; }
    else if (rr < 960) { l = 4; j = rr - 896; off0 = 896; }
    else               { l = 5; j = rr - 960; off0 = 960; }
    int len = L0LEN[b * 992 + off0 + j];
    const int* st = SET0 + b * 5120 + (l - 1) * 1024 + (j << l);
    const unsigned short* src = z + (size_t)b * 1024 * D_DIM;
    int cc = c * 8;
    bf16x8_t mx = *(const bf16x8_t*)(src + (size_t)st[0] * D_DIM + cc);
    for (int e = 1; e < len; ++e) {
      bf16x8_t a = *(const bf16x8_t*)(src + (size_t)st[e] * D_DIM + cc);
#pragma unroll
      for (int q = 0; q < 8; ++q)
        mx[q] = (bf2f((unsigned short)mx[q]) >= bf2f((unsigned short)a[q])) ? mx[q] : a[q];
    }
    size_t zo = (size_t)2560 * (2048 - (2048 >> l));
    int Tl = 1024 >> l;
    *(bf16x8_t*)(z + zo + ((size_t)b * Tl + j) * D_DIM + cc) = mx;
  }
}

// ---------------- L3: [408 L1-5 tiles] + [78 mat2] + [248 L1-5 inst] ---------
__global__ __launch_bounds__(256, 3) void l3_kernel(
    unsigned short* __restrict__ z1, unsigned short* __restrict__ z2,
    const int* __restrict__ SET5, const int* __restrict__ L5LEN,
    float* __restrict__ wsm, float* __restrict__ wss,
    float* __restrict__ wsInst, Tab tab) {
  __shared__ __align__(16) unsigned char smem[49152];
  int bx = blockIdx.x;
  int tid = threadIdx.x;

  if (bx < 408) {
    // ========== levels 1..5 temporal tiles ==========
    int g = tab.tileStart[1] + bx;
    int l = 1;
    while (g >= tab.tileStart[l + 1]) ++l;
    int T = tab.T[l], S = tab.S[l];
    int local = g - tab.tileStart[l];
    int npl = (S * (S + 1)) >> 1;
    int nid = (local % 8) * npl + local / 8;
    int b = nid / npl;
    int pr = nid % npl;
    int rb = 0, tt = pr;
    while (tt >= S - rb) { tt -= S - rb; ++rb; }
    int sg = rb + tt;
    tile_body(smem, tid, z1 + tab.zoff[l], z2 + tab.zoff[l], b, T, S, rb, sg,
              wsm + tab.wsoff[l], wss + tab.wsoff[l]);
  } else if (bx < 486) {
    // ========== mat2: levels 6..10 from level-5 origin sets ==========
    int g = (bx - 408) * 256 + tid;
    if (g >= 2 * 8 * 31 * 40) return;
    int c = g % 40;
    int t2 = g / 40;
    int rr = t2 % 31;
    int bzi = t2 / 31;
    int b = bzi & 7;
    unsigned short* z = (bzi >> 3) ? z2 : z1;
    int l, j, off5;
    if (rr < 16)      { l = 6;  j = rr;      off5 = 0; }
    else if (rr < 24) { l = 7;  j = rr - 16; off5 = 16; }
    else if (rr < 28) { l = 8;  j = rr - 24; off5 = 24; }
    else if (rr < 30) { l = 9;  j = rr - 28; off5 = 28; }
    else              { l = 10; j = rr - 30; off5 = 30; }
    int len = L5LEN[b * 32 + off5 + j];
    const int* st = SET5 + b * 160 + (l - 6) * 32 + (j << (l - 5));
    const unsigned short* src = z + (size_t)2560 * (2048 - 64) + (size_t)b * 32 * D_DIM;
    int cc = c * 8;
    bf16x8_t mx = *(const bf16x8_t*)(src + (size_t)st[0] * D_DIM + cc);
    for (int e = 1; e < len; ++e) {
      bf16x8_t a = *(const bf16x8_t*)(src + (size_t)st[e] * D_DIM + cc);
#pragma unroll
      for (int q = 0; q < 8; ++q)
        mx[q] = (bf2f((unsigned short)mx[q]) >= bf2f((unsigned short)a[q])) ? mx[q] : a[q];
    }
    size_t zo = (size_t)2560 * (2048 - (2048 >> l));
    int Tl = 1024 >> l;
    *(bf16x8_t*)(z + zo + ((size_t)b * Tl + j) * D_DIM + cc) = mx;
  } else {
    // ========== levels 1..5 instance ==========
    int iw = 1024 + (bx - 486) * 4 + (tid >> 6);
    if (iw < 2016) {
      int l = 1;
      while (iw >= tab.instStart[l + 1]) ++l;
      int t = iw - tab.instStart[l];
      float lsum = inst_wave(z1 + tab.zoff[l], z2 + tab.zoff[l], tab.T[l], t,
                             tid & 63);
      if ((tid & 63) == 0) wsInst[iw] = lsum * tab.scale[l];
    }
  }
}

// ---------------- final: combine + tiny temporal (6-9) + inst 6-10 ----------
__global__ __launch_bounds__(256) void final_kernel(
    const unsigned short* __restrict__ z1, const unsigned short* __restrict__ z2,
    const float* __restrict__ wsm, const float* __restrict__ wss,
    const float* __restrict__ wsInst, float* __restrict__ out, Tab tab,
    int nc) {
  int bx = blockIdx.x;
  int tid = threadIdx.x;

  if (bx < nc) {
    int g = bx * 256 + tid;
    float loss = 0.f;
    if (g < tab.totr) {
      int l = 0;
      while (g >= tab.rstart[l + 1]) ++l;
      int row = g - tab.rstart[l];
      int T = tab.T[l], N = 2 * T, S = tab.S[l];
      int b = row / N, r = row % N;
      const float* wm = wsm + tab.wsoff[l];
      const float* wv = wss + tab.wsoff[l];
      float m = NEGINF;
      for (int s = 0; s < S; ++s) m = fmaxf(m, wm[(b * S + s) * N + r]);
      float sv = 0.f;
      for (int s = 0; s < S; ++s) {
        int idx = (b * S + s) * N + r;
        sv += wv[idx] * __expf(wm[idx] - m);
      }
      const unsigned short* zz1 = z1 + tab.zoff[l];
      const unsigned short* zz2 = z2 + tab.zoff[l];
      int pos = (r < T) ? r + T : r - T;
      const bf16x8_t* za = (const bf16x8_t*)zrowb(zz1, zz2, b, T, r);
      const bf16x8_t* zp = (const bf16x8_t*)zrowb(zz1, zz2, b, T, pos);
      float dot = 0.f;
      for (int k = 0; k < D_DIM / 8; ++k) {
        bf16x8_t a = za[k], p = zp[k];
#pragma unroll
        for (int e = 0; e < 8; ++e)
          dot += bf2f((unsigned short)a[e]) * bf2f((unsigned short)p[e]);
      }
      loss = (m + logf(sv) - dot) * tab.scale[l];
    } else if (g < tab.totr + 2016) {
      loss = wsInst[g - tab.totr];
    }
    float v = loss;
#pragma unroll
    for (int o = 1; o < 64; o <<= 1) v += __shfl_xor(v, o);
    __shared__ float part[4];
    int w = tid >> 6;
    if ((tid & 63) == 0) part[w] = v;
    __syncthreads();
    if (tid == 0)
      atomicAdd(out, part[0] + part[1] + part[2] + part[3]);
  } else if (bx < nc + 8) {
    // ---- tiny temporal levels 6..9: one wave per (b, l), 32x32 MFMA ----
    int widx = (bx - nc) * 4 + (tid >> 6);
    int l = 6 + (widx >> 3), b = widx & 7;
    int T = tab.T[l], N = 2 * T;
    const unsigned short* zz1 = z1 + tab.zoff[l];
    const unsigned short* zz2 = z2 + tab.zoff[l];
    int lane = tid & 63;
    int col = lane & 31, h = lane >> 5;
    int rl = (col < N) ? col : 0;
    const unsigned short* rowp = (rl < T)
        ? zz1 + ((size_t)b * T + rl) * D_DIM
        : zz2 + ((size_t)b * T + (rl - T)) * D_DIM;
    rowp += h * 8;
    f32x16_t acc = (f32x16_t)(0.f);
#pragma unroll
    for (int m2 = 0; m2 < 20; ++m2) {
      bf16x8_t a = *(const bf16x8_t*)(rowp + m2 * 16);
      acc = __builtin_amdgcn_mfma_f32_32x32x16_bf16(a, a, acc, 0, 0, 0);
    }
    float lsum = 0.f;
#pragma unroll
    for (int rg = 0; rg < 16; ++rg) {
      int row = (rg & 3) + 8 * (rg >> 2) + 4 * h;
      float x = acc[rg];
      float xm = (col < N && row < N && col != row) ? x : NEGINF;
      float m = xm;
#pragma unroll
      for (int o = 1; o < 32; o <<= 1) m = fmaxf(m, __shfl_xor(m, o));
      float s = __expf(xm - m);
#pragma unroll
      for (int o = 1; o < 32; o <<= 1) s += __shfl_xor(s, o);
      int pos = (row < T) ? row + T : row - T;
      if (row < N && col == pos) lsum += m + __logf(s) - x;
    }
#pragma unroll
    for (int o = 1; o < 64; o <<= 1) lsum += __shfl_xor(lsum, o);
    if (lane == 0) atomicAdd(out, lsum * tab.scale[l]);
  } else {
    // ---- instance levels 6..10: one wave per t, direct atomic ----
    int widx = (bx - nc - 8) * 4 + (tid >> 6);
    if (widx < 31) {
      int iw = 2016 + widx;
      int l = 6;
      while (iw >= tab.instStart[l + 1]) ++l;
      int t = iw - tab.instStart[l];
      float lsum = inst_wave(z1 + tab.zoff[l], z2 + tab.zoff[l], tab.T[l], t,
                             tid & 63);
      if ((tid & 63) == 0) atomicAdd(out, lsum * tab.scale[l]);
    }
  }
}

extern "C" void kernel_launch(void* const* d_in, const int* in_sizes, int n_in,
                              void* d_out, int out_size, void* d_ws, size_t ws_size,
                              hipStream_t stream) {
  const float* z1_in = (const float*)d_in[0];
  const float* z2_in = (const float*)d_in[1];
  const int* time_in = (const int*)d_in[2];
  float* out = (float*)d_out;

  // ---- level tables ----
  Tab tab;
  int zo = 0, wso = 0, ts = 0, is = 0, rs = 0;
  for (int l = 0; l < 11; ++l) {
    int T = 1024 >> l, N = 2 * T;
    int S = (N >= 128) ? N / 128 : 1;
    tab.T[l] = T;
    tab.S[l] = S;
    tab.zoff[l] = zo;
    tab.scale[l] = 1.0f / (352.0f * (float)T);  // 0.5/(2*B*T)/11
    tab.tileStart[l] = ts;
    tab.instStart[l] = is;
    tab.wsoff[l] = (T > 1) ? wso : 0;
    tab.rstart[l] = rs;
    if (T > 1) {
      ts += 8 * ((S * (S + 1)) >> 1);
      wso += 8 * S * N;
      if (l <= 5) rs += 8 * N;   // combine covers temporal rows of levels 0..5
    }
    is += T;
    zo += 8 * T * D_DIM;
  }
  tab.tileStart[11] = ts;
  tab.instStart[11] = is;
  for (int l = 6; l <= 11; ++l) tab.rstart[l] = rs;
  tab.totTemp = ts;
  tab.totInst = is;
  tab.totr = rs;

  // ---- workspace carve ----
  char* w = (char*)d_ws;
  unsigned short* z1s = (unsigned short*)w; w += (size_t)zo * 2;
  unsigned short* z2s = (unsigned short*)w; w += (size_t)zo * 2;
  float* wsm = (float*)w; w += (size_t)wso * sizeof(float);
  float* wss = (float*)w; w += (size_t)wso * sizeof(float);
  float* wsInst = (float*)w; w += (size_t)is * sizeof(float);
  int* SET0 = (int*)w; w += (size_t)8 * 5120 * sizeof(int);
  int* L0LEN = (int*)w; w += (size_t)8 * 992 * sizeof(int);
  int* SET5 = (int*)w; w += (size_t)8 * 160 * sizeof(int);
  int* L5LEN = (int*)w; w += (size_t)8 * 32 * sizeof(int);

  int n0 = 8 * 1024 * D_DIM;
  int nconv = 2040;
  l1_kernel<<<8 + nconv, 256, 0, stream>>>(time_in, z1_in, z2_in, z1s, z2s,
                                           n0 / 4, out, out_size, nconv,
                                           SET0, L0LEN, SET5, L5LEN);
  l2_kernel<<<1088 + 256 + 2480, 256, 0, stream>>>(z1s, z2s, wsm, wss, wsInst,
                                                   SET0, L0LEN);
  l3_kernel<<<408 + 78 + 248, 256, 0, stream>>>(z1s, z2s, SET5, L5LEN,
                                                wsm, wss, wsInst, tab);
  int nc = (tab.totr + 2016 + 255) / 256;
  final_kernel<<<nc + 16, 256, 0, stream>>>(z1s, z2s, wsm, wss, wsInst, out,
                                            tab, nc);
}

// Round 16
// 123.445 us; speedup vs baseline: 1.0820x; 1.0820x over previous
//
#include <hip/hip_runtime.h>
#include <cstdint>
#include <cstddef>

#define D_DIM 320
#define NEGINF (-1e30f)

typedef __attribute__((ext_vector_type(8))) short bf16x8_t;
typedef __attribute__((ext_vector_type(4))) float f32x4_t;
typedef __attribute__((ext_vector_type(16))) float f32x16_t;

struct Tab {
  int T[11], S[11], zoff[11], wsoff[11];
  int tileStart[12], instStart[12], rstart[12];
  float scale[11];
  int totTemp, totInst, totr;
};

__device__ __forceinline__ float bf2f(unsigned short u) {
  union { unsigned int i; float f; } v; v.i = ((unsigned int)u) << 16; return v.f;
}
__device__ __forceinline__ unsigned short f2bf(float f) {
  union { float f; unsigned int i; } u; u.f = f;
  unsigned int b = u.i + 0x7FFFu + ((u.i >> 16) & 1u);
  return (unsigned short)(b >> 16);
}

__device__ __forceinline__ const unsigned short* zrowb(
    const unsigned short* __restrict__ z1, const unsigned short* __restrict__ z2,
    int b, int T, int r) {
  return (r < T) ? (z1 + ((size_t)b * T + r) * D_DIM)
                 : (z2 + ((size_t)b * T + (r - T)) * D_DIM);
}

#define GLOAD_LDS16(SRC, DST)                                                   \
  __builtin_amdgcn_global_load_lds(                                             \
      (const __attribute__((address_space(1))) void*)(SRC),                     \
      (__attribute__((address_space(3))) void*)(DST), 16, 0, 0)

// ---- ring-3 tile-engine macros: buffers at short-offsets 0/8192/16384 ----
#define BUF1 8192
#define BUF2 16384

#define STAGE(koff, bufofs)                                                     \
    do {                                                                        \
      GLOAD_LDS16(gA0 + (koff), dA0 + (bufofs));                                \
      GLOAD_LDS16(gA1 + (koff), dA1 + (bufofs));                                \
      GLOAD_LDS16(gB0 + (koff), dB0 + (bufofs));                                \
      GLOAD_LDS16(gB1 + (koff), dB1 + (bufofs));                                \
    } while (0)

#define PHASE3(k, bo, bo2, VM, DO_PF)                                           \
    do {                                                                        \
      asm volatile("s_waitcnt vmcnt(" #VM ")" ::: "memory");                    \
      __builtin_amdgcn_s_barrier();                                             \
      if (DO_PF) STAGE((k + 2) * 32, bo2);                                      \
      bf16x8_t af[4], bfr[4];                                                   \
      _Pragma("unroll")                                                         \
      for (int at = 0; at < 4; ++at)                                            \
        af[at] = *(const bf16x8_t*)(vA + (bo) + at * 128);                      \
      _Pragma("unroll")                                                         \
      for (int ct = 0; ct < 4; ++ct)                                            \
        bfr[ct] = *(const bf16x8_t*)(vB + (bo) + ct * 128);                     \
      asm volatile("s_waitcnt lgkmcnt(0)" ::: "memory");                        \
      __builtin_amdgcn_sched_barrier(0);                                        \
      __builtin_amdgcn_s_setprio(1);                                            \
      _Pragma("unroll")                                                         \
      for (int ct = 0; ct < 4; ++ct)                                            \
        _Pragma("unroll")                                                       \
        for (int at = 0; at < 4; ++at)                                          \
          acc[at][ct] = __builtin_amdgcn_mfma_f32_16x16x32_bf16(                \
              af[at], bfr[ct], acc[at][ct], 0, 0, 0);                           \
      __builtin_amdgcn_s_setprio(0);                                            \
    } while (0)

// ================= shared device helpers =================
// full 128x128 temporal tile body — R13-proven per-row two-pass LSE epilogue
__device__ __forceinline__ void tile_body(
    unsigned char* smem, int tid,
    const unsigned short* zz1, const unsigned short* zz2,
    int b, int T, int S, int rb, int sg,
    float* wm, float* wv) {
  int N = 2 * T;
  int row0 = rb * 128, col0 = sg * 128;
  int w = tid >> 6, lane = tid & 63;
  int lq = lane >> 4, lr = lane & 15;
  int wr = w >> 1, wc = w & 1;

  unsigned short* lds = (unsigned short*)smem;

  int ra0 = row0 + lane;        if (ra0 > N - 1) ra0 = N - 1;
  int ra1 = row0 + 64 + lane;   if (ra1 > N - 1) ra1 = N - 1;
  int ca0 = col0 + lane;        if (ca0 > N - 1) ca0 = N - 1;
  int ca1 = col0 + 64 + lane;   if (ca1 > N - 1) ca1 = N - 1;
  const unsigned short* gA0 = zrowb(zz1, zz2, b, T, ra0) + w * 8;
  const unsigned short* gA1 = zrowb(zz1, zz2, b, T, ra1) + w * 8;
  const unsigned short* gB0 = zrowb(zz1, zz2, b, T, ca0) + w * 8;
  const unsigned short* gB1 = zrowb(zz1, zz2, b, T, ca1) + w * 8;
  unsigned short* dA0 = &lds[((w) * 128 + lane) * 8];
  unsigned short* dA1 = &lds[((w) * 128 + 64 + lane) * 8];
  unsigned short* dB0 = &lds[((4 + w) * 128 + lane) * 8];
  unsigned short* dB1 = &lds[((4 + w) * 128 + 64 + lane) * 8];

  f32x4_t acc[4][4];
#pragma unroll
  for (int at = 0; at < 4; ++at)
#pragma unroll
    for (int ct = 0; ct < 4; ++ct) acc[at][ct] = (f32x4_t)(0.f);

  const unsigned short* vA = &lds[((lq) * 128 + wr * 64 + lr) * 8];
  const unsigned short* vB = &lds[((4 + lq) * 128 + wc * 64 + lr) * 8];

  STAGE(0, 0);
  STAGE(32, BUF1);
  PHASE3(0, 0,    BUF2, 4, 1);
  PHASE3(1, BUF1, 0,    4, 1);
  PHASE3(2, BUF2, BUF1, 4, 1);
  PHASE3(3, 0,    BUF2, 4, 1);
  PHASE3(4, BUF1, 0,    4, 1);
  PHASE3(5, BUF2, BUF1, 4, 1);
  PHASE3(6, 0,    BUF2, 4, 1);
  PHASE3(7, BUF1, 0,    4, 1);
  PHASE3(8, BUF2, 0,    4, 0);
  PHASE3(9, 0,    0,    0, 0);
  __builtin_amdgcn_s_barrier();  // staging dead; alias epilogue into buffer0

  float (*mS)[128] = (float(*)[128])(smem);
  float (*sS)[128] = (float(*)[128])(smem + 1024);
  float (*mC)[128] = (float(*)[128])(smem + 2048);
  float (*sC)[128] = (float(*)[128])(smem + 3072);

  // row-LSE -> partial (col-seg sg)
#pragma unroll
  for (int at = 0; at < 4; ++at) {
#pragma unroll
    for (int rg = 0; rg < 4; ++rg) {
      int rloc = wr * 64 + at * 16 + lq * 4 + rg;
      int rglob = row0 + rloc;
      float v[4];
#pragma unroll
      for (int ct = 0; ct < 4; ++ct) {
        int cg = col0 + wc * 64 + ct * 16 + lr;
        v[ct] = (cg < N && cg != rglob) ? acc[at][ct][rg] : NEGINF;
      }
      float m = fmaxf(fmaxf(v[0], v[1]), fmaxf(v[2], v[3]));
#pragma unroll
      for (int o = 1; o < 16; o <<= 1) m = fmaxf(m, __shfl_xor(m, o));
      float sv = __expf(v[0] - m) + __expf(v[1] - m) +
                 __expf(v[2] - m) + __expf(v[3] - m);
#pragma unroll
      for (int o = 1; o < 16; o <<= 1) sv += __shfl_xor(sv, o);
      if (lr == 0) { mS[wc][rloc] = m; sS[wc][rloc] = sv; }
    }
  }
  // col-LSE (symmetry) -> partial (col-seg rb); off-diag tiles only
  if (rb != sg) {
#pragma unroll
    for (int ct = 0; ct < 4; ++ct) {
      float m = NEGINF;
#pragma unroll
      for (int at = 0; at < 4; ++at)
#pragma unroll
        for (int rg = 0; rg < 4; ++rg) m = fmaxf(m, acc[at][ct][rg]);
      m = fmaxf(m, __shfl_xor(m, 16));
      m = fmaxf(m, __shfl_xor(m, 32));
      float s = 0.f;
#pragma unroll
      for (int at = 0; at < 4; ++at)
#pragma unroll
        for (int rg = 0; rg < 4; ++rg) s += __expf(acc[at][ct][rg] - m);
      s += __shfl_xor(s, 16);
      s += __shfl_xor(s, 32);
      if (lq == 0) {
        mC[wr][wc * 64 + ct * 16 + lr] = m;
        sC[wr][wc * 64 + ct * 16 + lr] = s;
      }
    }
  }
  __syncthreads();

  if (tid < 128) {
    int rglob = row0 + tid;
    if (rglob < N) {
      float m0 = mS[0][tid], m1 = mS[1][tid];
      float m = fmaxf(m0, m1);
      float sv = sS[0][tid] * __expf(m0 - m) + sS[1][tid] * __expf(m1 - m);
      int idx = (b * S + sg) * N + rglob;
      wm[idx] = m;
      wv[idx] = sv;
    }
    if (rb != sg) {
      float m0 = mC[0][tid], m1 = mC[1][tid];
      float m = fmaxf(m0, m1);
      float sv = sC[0][tid] * __expf(m0 - m) + sC[1][tid] * __expf(m1 - m);
      int idx = (b * S + rb) * N + col0 + tid;
      wm[idx] = m;
      wv[idx] = sv;
    }
  }
}

// instance (16x16, one wave per t): returns wave loss sum (valid at lane 0)
__device__ __forceinline__ float inst_wave(
    const unsigned short* zz1, const unsigned short* zz2, int T, int t, int lane) {
  int lq = lane >> 4, lr = lane & 15;
  const unsigned short* zr = (lr < 8)
      ? zz1 + ((size_t)lr * T + t) * D_DIM
      : zz2 + ((size_t)(lr - 8) * T + t) * D_DIM;
  zr += lq * 8;
  f32x4_t c = (f32x4_t)(0.f);
#pragma unroll
  for (int k = 0; k < 10; ++k) {
    bf16x8_t a = *(const bf16x8_t*)(zr + k * 32);
    c = __builtin_amdgcn_mfma_f32_16x16x32_bf16(a, a, c, 0, 0, 0);
  }
  float lsum = 0.f;
#pragma unroll
  for (int rg = 0; rg < 4; ++rg) {
    int rrow = lq * 4 + rg;
    float v = c[rg];
    float x = (lr != rrow) ? v : NEGINF;
    float m = x;
#pragma unroll
    for (int o = 1; o < 16; o <<= 1) m = fmaxf(m, __shfl_xor(m, o));
    float s = __expf(x - m);
#pragma unroll
    for (int o = 1; o < 16; o <<= 1) s += __shfl_xor(s, o);
    int pos = (rrow < 8) ? rrow + 8 : rrow - 8;
    if (lr == pos) lsum += m + __logf(s) - v;
  }
#pragma unroll
  for (int o = 1; o < 64; o <<= 1) lsum += __shfl_xor(lsum, o);
  return lsum;
}

// per-row combine of temporal partials (one row per thread); block-reduced
__device__ __forceinline__ void combine_rows(
    const unsigned short* zz1, const unsigned short* zz2,
    const float* wm, const float* wv,
    int T, int S, float scale, int b, int r, bool valid,
    float* out, int tid) {
  int N = 2 * T;
  float loss = 0.f;
  if (valid) {
    float m = NEGINF;
    for (int s = 0; s < S; ++s) m = fmaxf(m, wm[(b * S + s) * N + r]);
    float sv = 0.f;
    for (int s = 0; s < S; ++s) {
      int idx = (b * S + s) * N + r;
      sv += wv[idx] * __expf(wm[idx] - m);
    }
    int pos = (r < T) ? r + T : r - T;
    const bf16x8_t* za = (const bf16x8_t*)zrowb(zz1, zz2, b, T, r);
    const bf16x8_t* zp = (const bf16x8_t*)zrowb(zz1, zz2, b, T, pos);
    float dot = 0.f;
    for (int k = 0; k < D_DIM / 8; ++k) {
      bf16x8_t a = za[k], p = zp[k];
#pragma unroll
      for (int e = 0; e < 8; ++e)
        dot += bf2f((unsigned short)a[e]) * bf2f((unsigned short)p[e]);
    }
    loss = (m + logf(sv) - dot) * scale;
  }
  float v = loss;
#pragma unroll
  for (int o = 1; o < 64; o <<= 1) v += __shfl_xor(v, o);
  __shared__ float part[4];
  int w = tid >> 6;
  if ((tid & 63) == 0) part[w] = v;
  __syncthreads();
  if (tid == 0)
    atomicAdd(out, part[0] + part[1] + part[2] + part[3]);
}

// ---------------- convert: fp32 -> bf16 + zero out ----------------
__global__ __launch_bounds__(256) void convert_kernel(
    const float* __restrict__ i1, const float* __restrict__ i2,
    unsigned short* __restrict__ o1, unsigned short* __restrict__ o2,
    int n4, float* __restrict__ out, int outn) {
  int i = blockIdx.x * 256 + threadIdx.x;
  if (i < outn) out[i] = 0.f;
  int stride = gridDim.x * 256;
  for (int j = i; j < n4; j += stride) {
    float4 v = ((const float4*)i1)[j];
    ushort4 r;
    r.x = f2bf(v.x); r.y = f2bf(v.y); r.z = f2bf(v.z); r.w = f2bf(v.w);
    ((ushort4*)o1)[j] = r;
    float4 u = ((const float4*)i2)[j];
    ushort4 q;
    q.x = f2bf(u.x); q.y = f2bf(u.y); q.z = f2bf(u.z); q.w = f2bf(u.w);
    ((ushort4*)o2)[j] = q;
  }
}

// ---------------- work0: [8 sort blocks] + [1088 L0 tiles] + [256 L0 inst] ---
__global__ __launch_bounds__(256, 3) void work0_kernel(
    const int* __restrict__ time0,
    const unsigned short* __restrict__ z1, const unsigned short* __restrict__ z2,
    float* __restrict__ wsm, float* __restrict__ wss,
    float* __restrict__ wsInst,
    int* __restrict__ SET0, int* __restrict__ L0LEN,
    int* __restrict__ SET5, int* __restrict__ L5LEN) {
  __shared__ __align__(16) unsigned char smem[49152];
  int bx = blockIdx.x;
  int tid = threadIdx.x;

  if (bx < 8) {
    // ===== bucket-rank stable argsort + origin-set expansion =====
    int b = bx;
    int lane = tid & 63, wid = tid >> 6;
    int* tcur = (int*)smem;
    unsigned* hist = (unsigned*)(smem + 4096);
    unsigned* cum = (unsigned*)(smem + 8192);
    unsigned long long* arr = (unsigned long long*)(smem + 12288);
    int* sortedIdx = (int*)(smem + 20480);
    int* tnew = (int*)(smem + 24576);
    int* srcK = (int*)(smem + 26624);
    int* setA = (int*)(smem + 28672);
    int* setB = (int*)(smem + 32768);
    int* lenA = (int*)(smem + 36864);
    int* lenB = (int*)(smem + 40960);
    unsigned* minW = (unsigned*)(smem + 43008);
    unsigned* maxW = (unsigned*)(smem + 43072);
    unsigned* wsum = (unsigned*)(smem + 43136);
    int* wcnt = (int*)(smem + 43200);

#pragma unroll
    for (int i = 0; i < 4; ++i) {
      int e = tid + 256 * i;
      tcur[e] = time0[b * 1024 + e];
      setA[e] = e;
      lenA[e] = 1;
    }
    __syncthreads();

    int pp = 0;
    for (int lvl = 1; lvl <= 10; ++lvl) {
      int T = 2048 >> lvl;
      int n = T - 1, half = T >> 1;
      bool act[4];
      int dd[4];
      unsigned bkey[4];
      unsigned mn = 0xFFFFFFFFu, mx = 0u;
#pragma unroll
      for (int i = 0; i < 4; ++i) {
        int e = tid + 256 * i;
        act[i] = e < n;
        dd[i] = 0; bkey[i] = 0;
        if (act[i]) {
          dd[i] = tcur[e + 1] - tcur[e];
          bkey[i] = __float_as_uint((float)dd[i]);
          mn = mn < bkey[i] ? mn : bkey[i];
          mx = mx > bkey[i] ? mx : bkey[i];
        }
        hist[e] = 0;
      }
#pragma unroll
      for (int o = 1; o < 64; o <<= 1) {
        unsigned m2 = (unsigned)__shfl_xor((int)mn, o);
        unsigned x2 = (unsigned)__shfl_xor((int)mx, o);
        mn = mn < m2 ? mn : m2;
        mx = mx > x2 ? mx : x2;
      }
      if (lane == 0) { minW[wid] = mn; maxW[wid] = mx; }
      __syncthreads();

      unsigned bmin = 0xFFFFFFFFu, bmax = 0;
#pragma unroll
      for (int i = 0; i < 4; ++i) {
        bmin = bmin < minW[i] ? bmin : minW[i];
        bmax = bmax > maxW[i] ? bmax : maxW[i];
      }
      unsigned long long range = (unsigned long long)(bmax - bmin) + 1;
      unsigned long long scl = (1024ULL << 30) / range;
      int bkt[4]; unsigned av[4];
#pragma unroll
      for (int i = 0; i < 4; ++i) {
        if (act[i]) {
          int bk = (int)(((unsigned long long)(bkey[i] - bmin) * scl) >> 30);
          bkt[i] = bk > 1023 ? 1023 : bk;
          av[i] = atomicAdd(&hist[bkt[i]], 1u);
        }
      }
      __syncthreads();

      {  // exclusive scan over 1024 bins: 4 bins/thread
        unsigned l0 = hist[4 * tid], l1 = hist[4 * tid + 1],
                 l2 = hist[4 * tid + 2], l3 = hist[4 * tid + 3];
        unsigned s = l0 + l1 + l2 + l3;
        unsigned inc = s;
#pragma unroll
        for (int o = 1; o < 64; o <<= 1) {
          unsigned t = (unsigned)__shfl_up((int)inc, o);
          if (lane >= o) inc += t;
        }
        if (lane == 63) wsum[wid] = inc;
        __syncthreads();
        unsigned wpre = 0;
        for (int j = 0; j < wid; ++j) wpre += wsum[j];
        unsigned ex = wpre + inc - s;
        cum[4 * tid] = ex;
        cum[4 * tid + 1] = ex + l0;
        cum[4 * tid + 2] = ex + l0 + l1;
        cum[4 * tid + 3] = ex + l0 + l1 + l2;
      }
      __syncthreads();

      unsigned long long key[4];
      int base[4], occ[4];
#pragma unroll
      for (int i = 0; i < 4; ++i) {
        base[i] = 0; occ[i] = 0;
        if (act[i]) {
          key[i] = ((unsigned long long)(unsigned)dd[i] << 10) |
                   (unsigned)(tid + 256 * i);
          base[i] = (int)cum[bkt[i]];
          arr[base[i] + av[i]] = key[i];
        }
      }
      __syncthreads();

      // interleaved 4-wide within-bucket rank count (latency-hidden)
      int cnt[4] = {0, 0, 0, 0};
      int mocc = 0;
#pragma unroll
      for (int i = 0; i < 4; ++i) {
        if (act[i]) {
          occ[i] = (int)hist[bkt[i]];
          mocc = occ[i] > mocc ? occ[i] : mocc;
        }
      }
      for (int j = 0; j < mocc; ++j) {
#pragma unroll
        for (int i = 0; i < 4; ++i)
          if (j < occ[i]) cnt[i] += (arr[base[i] + j] < key[i]) ? 1 : 0;
      }
#pragma unroll
      for (int i = 0; i < 4; ++i)
        if (act[i]) sortedIdx[base[i] + cnt[i]] = tid + 256 * i;
      __syncthreads();

      bool msk[4]; int rw[4];
#pragma unroll
      for (int i = 0; i < 4; ++i) {
        int k = tid + 256 * i;
        msk[i] = (k < n) && (sortedIdx[k] < half);
        unsigned long long bal = __ballot(msk[i]);
        rw[i] = __popcll(bal & ((1ull << lane) - 1ull));
        if (lane == 0) wcnt[i * 4 + wid] = (int)__popcll(bal);
      }
      __syncthreads();
#pragma unroll
      for (int i = 0; i < 4; ++i) {
        if (msk[i]) {
          int seg = i * 4 + wid;
          int pre = 0;
          for (int j = 0; j < seg; ++j) pre += wcnt[j];
          int rr = pre + rw[i];
          int k = tid + 256 * i;
          srcK[rr] = k;
          tnew[rr] = (tcur[k] + tcur[k + 1]) >> 1;
        }
      }
      __syncthreads();

      if (lvl == 6) {
        int* sp = pp ? setB : setA;
        int* lp = pp ? lenB : lenA;
        if (tid < 32) { sp[tid] = tid; lp[tid] = 1; }
        __syncthreads();
      }
      {
        int ll = (lvl <= 5) ? lvl : (lvl - 5);
        int* sp = pp ? setB : setA;
        int* lp = pp ? lenB : lenA;
        int* sc = pp ? setA : setB;
        int* lc = pp ? lenA : lenB;
        int *gset, *glen;
        if (lvl <= 5) {
          gset = SET0 + b * 5120 + (lvl - 1) * 1024;
          glen = L0LEN + b * 992 + (1024 - (1024 >> (lvl - 1)));
        } else {
          gset = SET5 + b * 160 + (lvl - 6) * 32;
          glen = L5LEN + b * 32 + (32 - (32 >> (lvl - 6)));
        }
        int tmax = half << ll;
#pragma unroll
        for (int i = 0; i < 4; ++i) {
          int s = tid + 256 * i;
          if (s < tmax) {
            int j = s >> ll, e2 = s & ((1 << ll) - 1);
            int k = srcK[j];
            int la = lp[k], lb2 = lp[k + 1];
            int v = -1;
            int sh = ll - 1;
            if (e2 < la) v = sp[(k << sh) + e2];
            else if (e2 < la + lb2) v = sp[((k + 1) << sh) + (e2 - la)];
            if (e2 == 0) { lc[j] = la + lb2; glen[j] = la + lb2; }
            if (v >= 0) { sc[s] = v; gset[s] = v; }
          }
        }
        __syncthreads();
        pp ^= 1;
      }
#pragma unroll
      for (int i = 0; i < 4; ++i) {
        int j = tid + 256 * i;
        if (j < half) tcur[j] = tnew[j];
      }
      __syncthreads();
    }
  } else if (bx < 8 + 1088) {
    // ========== level-0 temporal tile (rb<=sg) ==========
    const int T = 1024, S = 16;
    int local = bx - 8;
    int b = local % 8;
    int pr = local / 8;
    int rb = 0, tt = pr;
    while (tt >= S - rb) { tt -= S - rb; ++rb; }
    int sg = rb + tt;
    tile_body(smem, tid, z1, z2, b, T, S, rb, sg, wsm, wss);
  } else {
    // ========== level-0 instance: one wave per t ==========
    int iw = (bx - 1096) * 4 + (tid >> 6);
    float lsum = inst_wave(z1, z2, 1024, iw, tid & 63);
    if ((tid & 63) == 0) wsInst[iw] = lsum * (1.0f / 360448.0f);
  }
}

// ---------------- mat1: z levels 1..5 = max over level-0 origin sets ---------
__global__ __launch_bounds__(256) void mat1_kernel(
    unsigned short* __restrict__ z1, unsigned short* __restrict__ z2,
    const int* __restrict__ SET0, const int* __restrict__ L0LEN) {
  int g = blockIdx.x * 256 + threadIdx.x;  // exact grid: 2*8*992*40
  int c = g % 40;
  int t2 = g / 40;
  int rr = t2 % 992;
  int bzi = t2 / 992;
  int b = bzi & 7;
  unsigned short* z = (bzi >> 3) ? z2 : z1;
  int l, j, off0;
  if (rr < 512)      { l = 1; j = rr;       off0 = 0; }
  else if (rr < 768) { l = 2; j = rr - 512; off0 = 512; }
  else if (rr < 896) { l = 3; j = rr - 768; off0 = 768; }
  else if (rr < 960) { l = 4; j = rr - 896; off0 = 896; }
  else               { l = 5; j = rr - 960; off0 = 960; }
  int len = L0LEN[b * 992 + off0 + j];
  const int* st = SET0 + b * 5120 + (l - 1) * 1024 + (j << l);
  const unsigned short* src = z + (size_t)b * 1024 * D_DIM;
  int cc = c * 8;
  bf16x8_t mx = *(const bf16x8_t*)(src + (size_t)st[0] * D_DIM + cc);
  for (int e = 1; e < len; ++e) {
    bf16x8_t a = *(const bf16x8_t*)(src + (size_t)st[e] * D_DIM + cc);
#pragma unroll
    for (int q = 0; q < 8; ++q)
      mx[q] = (bf2f((unsigned short)mx[q]) >= bf2f((unsigned short)a[q])) ? mx[q] : a[q];
  }
  size_t zo = (size_t)2560 * (2048 - (2048 >> l));
  int Tl = 1024 >> l;
  *(bf16x8_t*)(z + zo + ((size_t)b * Tl + j) * D_DIM + cc) = mx;
}

// ---------------- l3: [408 L1-5 tiles] + [78 mat2] + [248 L1-5 inst]
//                  + [64 L0-row combine] ----------------
__global__ __launch_bounds__(256, 3) void l3_kernel(
    unsigned short* __restrict__ z1, unsigned short* __restrict__ z2,
    const int* __restrict__ SET5, const int* __restrict__ L5LEN,
    float* __restrict__ wsm, float* __restrict__ wss,
    float* __restrict__ wsInst, float* __restrict__ out, Tab tab) {
  __shared__ __align__(16) unsigned char smem[49152];
  int bx = blockIdx.x;
  int tid = threadIdx.x;

  if (bx < 408) {
    // ========== levels 1..5 temporal tiles ==========
    int g = tab.tileStart[1] + bx;
    int l = 1;
    while (g >= tab.tileStart[l + 1]) ++l;
    int T = tab.T[l], S = tab.S[l];
    int local = g - tab.tileStart[l];
    int npl = (S * (S + 1)) >> 1;
    int nid = (local % 8) * npl + local / 8;
    int b = nid / npl;
    int pr = nid % npl;
    int rb = 0, tt = pr;
    while (tt >= S - rb) { tt -= S - rb; ++rb; }
    int sg = rb + tt;
    tile_body(smem, tid, z1 + tab.zoff[l], z2 + tab.zoff[l], b, T, S, rb, sg,
              wsm + tab.wsoff[l], wss + tab.wsoff[l]);
  } else if (bx < 486) {
    // ========== mat2: levels 6..10 from level-5 origin sets ==========
    int g = (bx - 408) * 256 + tid;
    if (g >= 2 * 8 * 31 * 40) return;
    int c = g % 40;
    int t2 = g / 40;
    int rr = t2 % 31;
    int bzi = t2 / 31;
    int b = bzi & 7;
    unsigned short* z = (bzi >> 3) ? z2 : z1;
    int l, j, off5;
    if (rr < 16)      { l = 6;  j = rr;      off5 = 0; }
    else if (rr < 24) { l = 7;  j = rr - 16; off5 = 16; }
    else if (rr < 28) { l = 8;  j = rr - 24; off5 = 24; }
    else if (rr < 30) { l = 9;  j = rr - 28; off5 = 28; }
    else              { l = 10; j = rr - 30; off5 = 30; }
    int len = L5LEN[b * 32 + off5 + j];
    const int* st = SET5 + b * 160 + (l - 6) * 32 + (j << (l - 5));
    const unsigned short* src = z + (size_t)2560 * (2048 - 64) + (size_t)b * 32 * D_DIM;
    int cc = c * 8;
    bf16x8_t mx = *(const bf16x8_t*)(src + (size_t)st[0] * D_DIM + cc);
    for (int e = 1; e < len; ++e) {
      bf16x8_t a = *(const bf16x8_t*)(src + (size_t)st[e] * D_DIM + cc);
#pragma unroll
      for (int q = 0; q < 8; ++q)
        mx[q] = (bf2f((unsigned short)mx[q]) >= bf2f((unsigned short)a[q])) ? mx[q] : a[q];
    }
    size_t zo = (size_t)2560 * (2048 - (2048 >> l));
    int Tl = 1024 >> l;
    *(bf16x8_t*)(z + zo + ((size_t)b * Tl + j) * D_DIM + cc) = mx;
  } else if (bx < 734) {
    // ========== levels 1..5 instance ==========
    int iw = 1024 + (bx - 486) * 4 + (tid >> 6);
    if (iw < 2016) {
      int l = 1;
      while (iw >= tab.instStart[l + 1]) ++l;
      int t = iw - tab.instStart[l];
      float lsum = inst_wave(z1 + tab.zoff[l], z2 + tab.zoff[l], tab.T[l], t,
                             tid & 63);
      if ((tid & 63) == 0) wsInst[iw] = lsum * tab.scale[l];
    }
  } else {
    // ========== level-0 temporal-row combine (16384 rows) ==========
    int g = (bx - 734) * 256 + tid;
    int b = g >> 11, r = g & 2047;
    combine_rows(z1, z2, wsm, wss, 1024, 16, tab.scale[0], b, r, true, out, tid);
  }
}

// ---------------- final: combine L1-5 rows + inst partials +
//                  tiny temporal (6-9) + inst 6-10 ----------------
__global__ __launch_bounds__(256) void final_kernel(
    const unsigned short* __restrict__ z1, const unsigned short* __restrict__ z2,
    const float* __restrict__ wsm, const float* __restrict__ wss,
    const float* __restrict__ wsInst, float* __restrict__ out, Tab tab,
    int nc) {
  int bx = blockIdx.x;
  int tid = threadIdx.x;

  if (bx < nc) {
    int g = bx * 256 + tid + 16384;  // skip level-0 rows (handled in l3)
    float loss = 0.f;
    if (g < tab.totr) {
      int l = 0;
      while (g >= tab.rstart[l + 1]) ++l;
      int row = g - tab.rstart[l];
      int T = tab.T[l], N = 2 * T, S = tab.S[l];
      int b = row / N, r = row % N;
      const float* wm = wsm + tab.wsoff[l];
      const float* wv = wss + tab.wsoff[l];
      float m = NEGINF;
      for (int s = 0; s < S; ++s) m = fmaxf(m, wm[(b * S + s) * N + r]);
      float sv = 0.f;
      for (int s = 0; s < S; ++s) {
        int idx = (b * S + s) * N + r;
        sv += wv[idx] * __expf(wm[idx] - m);
      }
      const unsigned short* zz1 = z1 + tab.zoff[l];
      const unsigned short* zz2 = z2 + tab.zoff[l];
      int pos = (r < T) ? r + T : r - T;
      const bf16x8_t* za = (const bf16x8_t*)zrowb(zz1, zz2, b, T, r);
      const bf16x8_t* zp = (const bf16x8_t*)zrowb(zz1, zz2, b, T, pos);
      float dot = 0.f;
      for (int k = 0; k < D_DIM / 8; ++k) {
        bf16x8_t a = za[k], p = zp[k];
#pragma unroll
        for (int e = 0; e < 8; ++e)
          dot += bf2f((unsigned short)a[e]) * bf2f((unsigned short)p[e]);
      }
      loss = (m + logf(sv) - dot) * tab.scale[l];
    } else if (g < tab.totr + 2016) {
      loss = wsInst[g - tab.totr];
    }
    float v = loss;
#pragma unroll
    for (int o = 1; o < 64; o <<= 1) v += __shfl_xor(v, o);
    __shared__ float part[4];
    int w = tid >> 6;
    if ((tid & 63) == 0) part[w] = v;
    __syncthreads();
    if (tid == 0)
      atomicAdd(out, part[0] + part[1] + part[2] + part[3]);
  } else if (bx < nc + 8) {
    // ---- tiny temporal levels 6..9: one wave per (b, l), 32x32 MFMA ----
    int widx = (bx - nc) * 4 + (tid >> 6);
    int l = 6 + (widx >> 3), b = widx & 7;
    int T = tab.T[l], N = 2 * T;
    const unsigned short* zz1 = z1 + tab.zoff[l];
    const unsigned short* zz2 = z2 + tab.zoff[l];
    int lane = tid & 63;
    int col = lane & 31, h = lane >> 5;
    int rl = (col < N) ? col : 0;
    const unsigned short* rowp = (rl < T)
        ? zz1 + ((size_t)b * T + rl) * D_DIM
        : zz2 + ((size_t)b * T + (rl - T)) * D_DIM;
    rowp += h * 8;
    f32x16_t acc = (f32x16_t)(0.f);
#pragma unroll
    for (int m2 = 0; m2 < 20; ++m2) {
      bf16x8_t a = *(const bf16x8_t*)(rowp + m2 * 16);
      acc = __builtin_amdgcn_mfma_f32_32x32x16_bf16(a, a, acc, 0, 0, 0);
    }
    float lsum = 0.f;
#pragma unroll
    for (int rg = 0; rg < 16; ++rg) {
      int row = (rg & 3) + 8 * (rg >> 2) + 4 * h;
      float x = acc[rg];
      float xm = (col < N && row < N && col != row) ? x : NEGINF;
      float m = xm;
#pragma unroll
      for (int o = 1; o < 32; o <<= 1) m = fmaxf(m, __shfl_xor(m, o));
      float s = __expf(xm - m);
#pragma unroll
      for (int o = 1; o < 32; o <<= 1) s += __shfl_xor(s, o);
      int pos = (row < T) ? row + T : row - T;
      if (row < N && col == pos) lsum += m + __logf(s) - x;
    }
#pragma unroll
    for (int o = 1; o < 64; o <<= 1) lsum += __shfl_xor(lsum, o);
    if (lane == 0) atomicAdd(out, lsum * tab.scale[l]);
  } else {
    // ---- instance levels 6..10: one wave per t, direct atomic ----
    int widx = (bx - nc - 8) * 4 + (tid >> 6);
    if (widx < 31) {
      int iw = 2016 + widx;
      int l = 6;
      while (iw >= tab.instStart[l + 1]) ++l;
      int t = iw - tab.instStart[l];
      float lsum = inst_wave(z1 + tab.zoff[l], z2 + tab.zoff[l], tab.T[l], t,
                             tid & 63);
      if ((tid & 63) == 0) atomicAdd(out, lsum * tab.scale[l]);
    }
  }
}

extern "C" void kernel_launch(void* const* d_in, const int* in_sizes, int n_in,
                              void* d_out, int out_size, void* d_ws, size_t ws_size,
                              hipStream_t stream) {
  const float* z1_in = (const float*)d_in[0];
  const float* z2_in = (const float*)d_in[1];
  const int* time_in = (const int*)d_in[2];
  float* out = (float*)d_out;

  // ---- level tables ----
  Tab tab;
  int zo = 0, wso = 0, ts = 0, is = 0, rs = 0;
  for (int l = 0; l < 11; ++l) {
    int T = 1024 >> l, N = 2 * T;
    int S = (N >= 128) ? N / 128 : 1;
    tab.T[l] = T;
    tab.S[l] = S;
    tab.zoff[l] = zo;
    tab.scale[l] = 1.0f / (352.0f * (float)T);  // 0.5/(2*B*T)/11
    tab.tileStart[l] = ts;
    tab.instStart[l] = is;
    tab.wsoff[l] = (T > 1) ? wso : 0;
    tab.rstart[l] = rs;
    if (T > 1) {
      ts += 8 * ((S * (S + 1)) >> 1);
      wso += 8 * S * N;
      if (l <= 5) rs += 8 * N;   // combine covers temporal rows of levels 0..5
    }
    is += T;
    zo += 8 * T * D_DIM;
  }
  tab.tileStart[11] = ts;
  tab.instStart[11] = is;
  for (int l = 6; l <= 11; ++l) tab.rstart[l] = rs;
  tab.totTemp = ts;
  tab.totInst = is;
  tab.totr = rs;

  // ---- workspace carve ----
  char* w = (char*)d_ws;
  unsigned short* z1s = (unsigned short*)w; w += (size_t)zo * 2;
  unsigned short* z2s = (unsigned short*)w; w += (size_t)zo * 2;
  float* wsm = (float*)w; w += (size_t)wso * sizeof(float);
  float* wss = (float*)w; w += (size_t)wso * sizeof(float);
  float* wsInst = (float*)w; w += (size_t)is * sizeof(float);
  int* SET0 = (int*)w; w += (size_t)8 * 5120 * sizeof(int);
  int* L0LEN = (int*)w; w += (size_t)8 * 992 * sizeof(int);
  int* SET5 = (int*)w; w += (size_t)8 * 160 * sizeof(int);
  int* L5LEN = (int*)w; w += (size_t)8 * 32 * sizeof(int);

  int n0 = 8 * 1024 * D_DIM;
  convert_kernel<<<2048, 256, 0, stream>>>(z1_in, z2_in, z1s, z2s, n0 / 4,
                                           out, out_size);
  work0_kernel<<<8 + 1088 + 256, 256, 0, stream>>>(
      time_in, z1s, z2s, wsm, wss, wsInst, SET0, L0LEN, SET5, L5LEN);
  mat1_kernel<<<2480, 256, 0, stream>>>(z1s, z2s, SET0, L0LEN);
  l3_kernel<<<408 + 78 + 248 + 64, 256, 0, stream>>>(
      z1s, z2s, SET5, L5LEN, wsm, wss, wsInst, out, tab);
  int nc = (tab.totr - 16384 + 2016 + 255) / 256;
  final_kernel<<<nc + 16, 256, 0, stream>>>(z1s, z2s, wsm, wss, wsInst, out,
                                            tab, nc);
}

// Round 17
// 117.202 us; speedup vs baseline: 1.1396x; 1.0533x over previous
//
#include <hip/hip_runtime.h>
#include <cstdint>
#include <cstddef>

#define D_DIM 320
#define NEGINF (-1e30f)

typedef __attribute__((ext_vector_type(8))) short bf16x8_t;
typedef __attribute__((ext_vector_type(4))) float f32x4_t;
typedef __attribute__((ext_vector_type(16))) float f32x16_t;

struct Tab {
  int T[11], S[11], zoff[11], wsoff[11];
  int tileStart[12], instStart[12], rstart[12];
  float scale[11];
  int totTemp, totInst, totr;
};

__device__ __forceinline__ float bf2f(unsigned short u) {
  union { unsigned int i; float f; } v; v.i = ((unsigned int)u) << 16; return v.f;
}
__device__ __forceinline__ unsigned short f2bf(float f) {
  union { float f; unsigned int i; } u; u.f = f;
  unsigned int b = u.i + 0x7FFFu + ((u.i >> 16) & 1u);
  return (unsigned short)(b >> 16);
}

__device__ __forceinline__ const unsigned short* zrowb(
    const unsigned short* __restrict__ z1, const unsigned short* __restrict__ z2,
    int b, int T, int r) {
  return (r < T) ? (z1 + ((size_t)b * T + r) * D_DIM)
                 : (z2 + ((size_t)b * T + (r - T)) * D_DIM);
}

#define GLOAD_LDS16(SRC, DST)                                                   \
  __builtin_amdgcn_global_load_lds(                                             \
      (const __attribute__((address_space(1))) void*)(SRC),                     \
      (__attribute__((address_space(3))) void*)(DST), 16, 0, 0)

// ---- ring-3 tile-engine macros: buffers at short-offsets 0/8192/16384 ----
#define BUF1 8192
#define BUF2 16384

#define STAGE(koff, bufofs)                                                     \
    do {                                                                        \
      GLOAD_LDS16(gA0 + (koff), dA0 + (bufofs));                                \
      GLOAD_LDS16(gA1 + (koff), dA1 + (bufofs));                                \
      GLOAD_LDS16(gB0 + (koff), dB0 + (bufofs));                                \
      GLOAD_LDS16(gB1 + (koff), dB1 + (bufofs));                                \
    } while (0)

#define PHASE3(k, bo, bo2, VM, DO_PF)                                           \
    do {                                                                        \
      asm volatile("s_waitcnt vmcnt(" #VM ")" ::: "memory");                    \
      __builtin_amdgcn_s_barrier();                                             \
      if (DO_PF) STAGE((k + 2) * 32, bo2);                                      \
      bf16x8_t af[4], bfr[4];                                                   \
      _Pragma("unroll")                                                         \
      for (int at = 0; at < 4; ++at)                                            \
        af[at] = *(const bf16x8_t*)(vA + (bo) + at * 128);                      \
      _Pragma("unroll")                                                         \
      for (int ct = 0; ct < 4; ++ct)                                            \
        bfr[ct] = *(const bf16x8_t*)(vB + (bo) + ct * 128);                     \
      asm volatile("s_waitcnt lgkmcnt(0)" ::: "memory");                        \
      __builtin_amdgcn_sched_barrier(0);                                        \
      __builtin_amdgcn_s_setprio(1);                                            \
      _Pragma("unroll")                                                         \
      for (int ct = 0; ct < 4; ++ct)                                            \
        _Pragma("unroll")                                                       \
        for (int at = 0; at < 4; ++at)                                          \
          acc[at][ct] = __builtin_amdgcn_mfma_f32_16x16x32_bf16(                \
              af[at], bfr[ct], acc[at][ct], 0, 0, 0);                           \
      __builtin_amdgcn_s_setprio(0);                                            \
    } while (0)

// ================= shared device helpers =================
__device__ __forceinline__ void tile_body(
    unsigned char* smem, int tid,
    const unsigned short* zz1, const unsigned short* zz2,
    int b, int T, int S, int rb, int sg,
    float* wm, float* wv) {
  int N = 2 * T;
  int row0 = rb * 128, col0 = sg * 128;
  int w = tid >> 6, lane = tid & 63;
  int lq = lane >> 4, lr = lane & 15;
  int wr = w >> 1, wc = w & 1;

  unsigned short* lds = (unsigned short*)smem;

  int ra0 = row0 + lane;        if (ra0 > N - 1) ra0 = N - 1;
  int ra1 = row0 + 64 + lane;   if (ra1 > N - 1) ra1 = N - 1;
  int ca0 = col0 + lane;        if (ca0 > N - 1) ca0 = N - 1;
  int ca1 = col0 + 64 + lane;   if (ca1 > N - 1) ca1 = N - 1;
  const unsigned short* gA0 = zrowb(zz1, zz2, b, T, ra0) + w * 8;
  const unsigned short* gA1 = zrowb(zz1, zz2, b, T, ra1) + w * 8;
  const unsigned short* gB0 = zrowb(zz1, zz2, b, T, ca0) + w * 8;
  const unsigned short* gB1 = zrowb(zz1, zz2, b, T, ca1) + w * 8;
  unsigned short* dA0 = &lds[((w) * 128 + lane) * 8];
  unsigned short* dA1 = &lds[((w) * 128 + 64 + lane) * 8];
  unsigned short* dB0 = &lds[((4 + w) * 128 + lane) * 8];
  unsigned short* dB1 = &lds[((4 + w) * 128 + 64 + lane) * 8];

  f32x4_t acc[4][4];
#pragma unroll
  for (int at = 0; at < 4; ++at)
#pragma unroll
    for (int ct = 0; ct < 4; ++ct) acc[at][ct] = (f32x4_t)(0.f);

  const unsigned short* vA = &lds[((lq) * 128 + wr * 64 + lr) * 8];
  const unsigned short* vB = &lds[((4 + lq) * 128 + wc * 64 + lr) * 8];

  STAGE(0, 0);
  STAGE(32, BUF1);
  PHASE3(0, 0,    BUF2, 4, 1);
  PHASE3(1, BUF1, 0,    4, 1);
  PHASE3(2, BUF2, BUF1, 4, 1);
  PHASE3(3, 0,    BUF2, 4, 1);
  PHASE3(4, BUF1, 0,    4, 1);
  PHASE3(5, BUF2, BUF1, 4, 1);
  PHASE3(6, 0,    BUF2, 4, 1);
  PHASE3(7, BUF1, 0,    4, 1);
  PHASE3(8, BUF2, 0,    4, 0);
  PHASE3(9, 0,    0,    0, 0);
  __builtin_amdgcn_s_barrier();  // staging dead; alias epilogue into buffer0

  float (*mS)[128] = (float(*)[128])(smem);
  float (*sS)[128] = (float(*)[128])(smem + 1024);
  float (*mC)[128] = (float(*)[128])(smem + 2048);
  float (*sC)[128] = (float(*)[128])(smem + 3072);

  // row-LSE -> partial (col-seg sg)
#pragma unroll
  for (int at = 0; at < 4; ++at) {
#pragma unroll
    for (int rg = 0; rg < 4; ++rg) {
      int rloc = wr * 64 + at * 16 + lq * 4 + rg;
      int rglob = row0 + rloc;
      float v[4];
#pragma unroll
      for (int ct = 0; ct < 4; ++ct) {
        int cg = col0 + wc * 64 + ct * 16 + lr;
        v[ct] = (cg < N && cg != rglob) ? acc[at][ct][rg] : NEGINF;
      }
      float m = fmaxf(fmaxf(v[0], v[1]), fmaxf(v[2], v[3]));
#pragma unroll
      for (int o = 1; o < 16; o <<= 1) m = fmaxf(m, __shfl_xor(m, o));
      float sv = __expf(v[0] - m) + __expf(v[1] - m) +
                 __expf(v[2] - m) + __expf(v[3] - m);
#pragma unroll
      for (int o = 1; o < 16; o <<= 1) sv += __shfl_xor(sv, o);
      if (lr == 0) { mS[wc][rloc] = m; sS[wc][rloc] = sv; }
    }
  }
  // col-LSE (symmetry) -> partial (col-seg rb); off-diag tiles only
  if (rb != sg) {
#pragma unroll
    for (int ct = 0; ct < 4; ++ct) {
      float m = NEGINF;
#pragma unroll
      for (int at = 0; at < 4; ++at)
#pragma unroll
        for (int rg = 0; rg < 4; ++rg) m = fmaxf(m, acc[at][ct][rg]);
      m = fmaxf(m, __shfl_xor(m, 16));
      m = fmaxf(m, __shfl_xor(m, 32));
      float s = 0.f;
#pragma unroll
      for (int at = 0; at < 4; ++at)
#pragma unroll
        for (int rg = 0; rg < 4; ++rg) s += __expf(acc[at][ct][rg] - m);
      s += __shfl_xor(s, 16);
      s += __shfl_xor(s, 32);
      if (lq == 0) {
        mC[wr][wc * 64 + ct * 16 + lr] = m;
        sC[wr][wc * 64 + ct * 16 + lr] = s;
      }
    }
  }
  __syncthreads();

  if (tid < 128) {
    int rglob = row0 + tid;
    if (rglob < N) {
      float m0 = mS[0][tid], m1 = mS[1][tid];
      float m = fmaxf(m0, m1);
      float sv = sS[0][tid] * __expf(m0 - m) + sS[1][tid] * __expf(m1 - m);
      int idx = (b * S + sg) * N + rglob;
      wm[idx] = m;
      wv[idx] = sv;
    }
    if (rb != sg) {
      float m0 = mC[0][tid], m1 = mC[1][tid];
      float m = fmaxf(m0, m1);
      float sv = sC[0][tid] * __expf(m0 - m) + sC[1][tid] * __expf(m1 - m);
      int idx = (b * S + rb) * N + col0 + tid;
      wm[idx] = m;
      wv[idx] = sv;
    }
  }
}

// instance (16x16, one wave per t): returns wave loss sum (valid at lane 0)
__device__ __forceinline__ float inst_wave(
    const unsigned short* zz1, const unsigned short* zz2, int T, int t, int lane) {
  int lq = lane >> 4, lr = lane & 15;
  const unsigned short* zr = (lr < 8)
      ? zz1 + ((size_t)lr * T + t) * D_DIM
      : zz2 + ((size_t)(lr - 8) * T + t) * D_DIM;
  zr += lq * 8;
  f32x4_t c = (f32x4_t)(0.f);
#pragma unroll
  for (int k = 0; k < 10; ++k) {
    bf16x8_t a = *(const bf16x8_t*)(zr + k * 32);
    c = __builtin_amdgcn_mfma_f32_16x16x32_bf16(a, a, c, 0, 0, 0);
  }
  float lsum = 0.f;
#pragma unroll
  for (int rg = 0; rg < 4; ++rg) {
    int rrow = lq * 4 + rg;
    float v = c[rg];
    float x = (lr != rrow) ? v : NEGINF;
    float m = x;
#pragma unroll
    for (int o = 1; o < 16; o <<= 1) m = fmaxf(m, __shfl_xor(m, o));
    float s = __expf(x - m);
#pragma unroll
    for (int o = 1; o < 16; o <<= 1) s += __shfl_xor(s, o);
    int pos = (rrow < 8) ? rrow + 8 : rrow - 8;
    if (lr == pos) lsum += m + __logf(s) - v;
  }
#pragma unroll
  for (int o = 1; o < 64; o <<= 1) lsum += __shfl_xor(lsum, o);
  return lsum;
}

// ---------------- convert: fp32 -> bf16 + zero out ----------------
__global__ __launch_bounds__(256) void convert_kernel(
    const float* __restrict__ i1, const float* __restrict__ i2,
    unsigned short* __restrict__ o1, unsigned short* __restrict__ o2,
    int n4, float* __restrict__ out, int outn) {
  int i = blockIdx.x * 256 + threadIdx.x;
  if (i < outn) out[i] = 0.f;
  int stride = gridDim.x * 256;
  for (int j = i; j < n4; j += stride) {
    float4 v = ((const float4*)i1)[j];
    ushort4 r;
    r.x = f2bf(v.x); r.y = f2bf(v.y); r.z = f2bf(v.z); r.w = f2bf(v.w);
    ((ushort4*)o1)[j] = r;
    float4 u = ((const float4*)i2)[j];
    ushort4 q;
    q.x = f2bf(u.x); q.y = f2bf(u.y); q.z = f2bf(u.z); q.w = f2bf(u.w);
    ((ushort4*)o2)[j] = q;
  }
}

// ---------------- work0: [8 sort blocks] + [1088 L0 tiles] + [256 L0 inst] ---
__global__ __launch_bounds__(256, 3) void work0_kernel(
    const int* __restrict__ time0,
    const unsigned short* __restrict__ z1, const unsigned short* __restrict__ z2,
    float* __restrict__ wsm, float* __restrict__ wss,
    float* __restrict__ wsInst,
    int* __restrict__ SET0, int* __restrict__ L0LEN,
    int* __restrict__ SET5, int* __restrict__ L5LEN) {
  __shared__ __align__(16) unsigned char smem[49152];
  int bx = blockIdx.x;
  int tid = threadIdx.x;

  if (bx < 8) {
    // ===== bucket-rank stable argsort + origin-set expansion =====
    int b = bx;
    int lane = tid & 63, wid = tid >> 6;
    int* tcur = (int*)smem;
    unsigned* hist = (unsigned*)(smem + 4096);
    unsigned* cum = (unsigned*)(smem + 8192);
    unsigned long long* arr = (unsigned long long*)(smem + 12288);
    int* sortedIdx = (int*)(smem + 20480);
    int* tnew = (int*)(smem + 24576);
    int* srcK = (int*)(smem + 26624);
    int* setA = (int*)(smem + 28672);
    int* setB = (int*)(smem + 32768);
    int* lenA = (int*)(smem + 36864);
    int* lenB = (int*)(smem + 40960);
    unsigned* minW = (unsigned*)(smem + 43008);
    unsigned* maxW = (unsigned*)(smem + 43072);
    unsigned* wsum = (unsigned*)(smem + 43136);
    int* wcnt = (int*)(smem + 43200);

#pragma unroll
    for (int i = 0; i < 4; ++i) {
      int e = tid + 256 * i;
      tcur[e] = time0[b * 1024 + e];
      setA[e] = e;
      lenA[e] = 1;
    }
    __syncthreads();

    int pp = 0;
    for (int lvl = 1; lvl <= 10; ++lvl) {
      int T = 2048 >> lvl;
      int n = T - 1, half = T >> 1;
      bool act[4];
      int dd[4];
      unsigned bkey[4];
      unsigned mn = 0xFFFFFFFFu, mx = 0u;
#pragma unroll
      for (int i = 0; i < 4; ++i) {
        int e = tid + 256 * i;
        act[i] = e < n;
        dd[i] = 0; bkey[i] = 0;
        if (act[i]) {
          dd[i] = tcur[e + 1] - tcur[e];
          bkey[i] = __float_as_uint((float)dd[i]);
          mn = mn < bkey[i] ? mn : bkey[i];
          mx = mx > bkey[i] ? mx : bkey[i];
        }
        hist[e] = 0;
      }
#pragma unroll
      for (int o = 1; o < 64; o <<= 1) {
        unsigned m2 = (unsigned)__shfl_xor((int)mn, o);
        unsigned x2 = (unsigned)__shfl_xor((int)mx, o);
        mn = mn < m2 ? mn : m2;
        mx = mx > x2 ? mx : x2;
      }
      if (lane == 0) { minW[wid] = mn; maxW[wid] = mx; }
      __syncthreads();

      unsigned bmin = 0xFFFFFFFFu, bmax = 0;
#pragma unroll
      for (int i = 0; i < 4; ++i) {
        bmin = bmin < minW[i] ? bmin : minW[i];
        bmax = bmax > maxW[i] ? bmax : maxW[i];
      }
      unsigned long long range = (unsigned long long)(bmax - bmin) + 1;
      unsigned long long scl = (1024ULL << 30) / range;
      int bkt[4]; unsigned av[4];
#pragma unroll
      for (int i = 0; i < 4; ++i) {
        if (act[i]) {
          int bk = (int)(((unsigned long long)(bkey[i] - bmin) * scl) >> 30);
          bkt[i] = bk > 1023 ? 1023 : bk;
          av[i] = atomicAdd(&hist[bkt[i]], 1u);
        }
      }
      __syncthreads();

      {  // exclusive scan over 1024 bins: 4 bins/thread
        unsigned l0 = hist[4 * tid], l1 = hist[4 * tid + 1],
                 l2 = hist[4 * tid + 2], l3 = hist[4 * tid + 3];
        unsigned s = l0 + l1 + l2 + l3;
        unsigned inc = s;
#pragma unroll
        for (int o = 1; o < 64; o <<= 1) {
          unsigned t = (unsigned)__shfl_up((int)inc, o);
          if (lane >= o) inc += t;
        }
        if (lane == 63) wsum[wid] = inc;
        __syncthreads();
        unsigned wpre = 0;
        for (int j = 0; j < wid; ++j) wpre += wsum[j];
        unsigned ex = wpre + inc - s;
        cum[4 * tid] = ex;
        cum[4 * tid + 1] = ex + l0;
        cum[4 * tid + 2] = ex + l0 + l1;
        cum[4 * tid + 3] = ex + l0 + l1 + l2;
      }
      __syncthreads();

      unsigned long long key[4];
      int base[4], occ[4];
#pragma unroll
      for (int i = 0; i < 4; ++i) {
        base[i] = 0; occ[i] = 0;
        if (act[i]) {
          key[i] = ((unsigned long long)(unsigned)dd[i] << 10) |
                   (unsigned)(tid + 256 * i);
          base[i] = (int)cum[bkt[i]];
          arr[base[i] + av[i]] = key[i];
        }
      }
      __syncthreads();

      // interleaved 4-wide within-bucket rank count (latency-hidden)
      int cnt[4] = {0, 0, 0, 0};
      int mocc = 0;
#pragma unroll
      for (int i = 0; i < 4; ++i) {
        if (act[i]) {
          occ[i] = (int)hist[bkt[i]];
          mocc = occ[i] > mocc ? occ[i] : mocc;
        }
      }
      for (int j = 0; j < mocc; ++j) {
#pragma unroll
        for (int i = 0; i < 4; ++i)
          if (j < occ[i]) cnt[i] += (arr[base[i] + j] < key[i]) ? 1 : 0;
      }
#pragma unroll
      for (int i = 0; i < 4; ++i)
        if (act[i]) sortedIdx[base[i] + cnt[i]] = tid + 256 * i;
      __syncthreads();

      bool msk[4]; int rw[4];
#pragma unroll
      for (int i = 0; i < 4; ++i) {
        int k = tid + 256 * i;
        msk[i] = (k < n) && (sortedIdx[k] < half);
        unsigned long long bal = __ballot(msk[i]);
        rw[i] = __popcll(bal & ((1ull << lane) - 1ull));
        if (lane == 0) wcnt[i * 4 + wid] = (int)__popcll(bal);
      }
      __syncthreads();
#pragma unroll
      for (int i = 0; i < 4; ++i) {
        if (msk[i]) {
          int seg = i * 4 + wid;
          int pre = 0;
          for (int j = 0; j < seg; ++j) pre += wcnt[j];
          int rr = pre + rw[i];
          int k = tid + 256 * i;
          srcK[rr] = k;
          tnew[rr] = (tcur[k] + tcur[k + 1]) >> 1;
        }
      }
      __syncthreads();

      if (lvl == 6) {
        int* sp = pp ? setB : setA;
        int* lp = pp ? lenB : lenA;
        if (tid < 32) { sp[tid] = tid; lp[tid] = 1; }
        __syncthreads();
      }
      {
        int ll = (lvl <= 5) ? lvl : (lvl - 5);
        int* sp = pp ? setB : setA;
        int* lp = pp ? lenB : lenA;
        int* sc = pp ? setA : setB;
        int* lc = pp ? lenA : lenB;
        int *gset, *glen;
        if (lvl <= 5) {
          gset = SET0 + b * 5120 + (lvl - 1) * 1024;
          glen = L0LEN + b * 992 + (1024 - (1024 >> (lvl - 1)));
        } else {
          gset = SET5 + b * 160 + (lvl - 6) * 32;
          glen = L5LEN + b * 32 + (32 - (32 >> (lvl - 6)));
        }
        int tmax = half << ll;
#pragma unroll
        for (int i = 0; i < 4; ++i) {
          int s = tid + 256 * i;
          if (s < tmax) {
            int j = s >> ll, e2 = s & ((1 << ll) - 1);
            int k = srcK[j];
            int la = lp[k], lb2 = lp[k + 1];
            int v = -1;
            int sh = ll - 1;
            if (e2 < la) v = sp[(k << sh) + e2];
            else if (e2 < la + lb2) v = sp[((k + 1) << sh) + (e2 - la)];
            if (e2 == 0) { lc[j] = la + lb2; glen[j] = la + lb2; }
            if (v >= 0) { sc[s] = v; gset[s] = v; }
          }
        }
        __syncthreads();
        pp ^= 1;
      }
#pragma unroll
      for (int i = 0; i < 4; ++i) {
        int j = tid + 256 * i;
        if (j < half) tcur[j] = tnew[j];
      }
      __syncthreads();
    }
  } else if (bx < 8 + 1088) {
    // ========== level-0 temporal tile (rb<=sg) ==========
    const int T = 1024, S = 16;
    int local = bx - 8;
    int b = local % 8;
    int pr = local / 8;
    int rb = 0, tt = pr;
    while (tt >= S - rb) { tt -= S - rb; ++rb; }
    int sg = rb + tt;
    tile_body(smem, tid, z1, z2, b, T, S, rb, sg, wsm, wss);
  } else {
    // ========== level-0 instance: one wave per t ==========
    int iw = (bx - 1096) * 4 + (tid >> 6);
    float lsum = inst_wave(z1, z2, 1024, iw, tid & 63);
    if ((tid & 63) == 0) wsInst[iw] = lsum * (1.0f / 360448.0f);
  }
}

// ---------------- mat1: z levels 1..5 = max over level-0 origin sets ---------
__global__ __launch_bounds__(256) void mat1_kernel(
    unsigned short* __restrict__ z1, unsigned short* __restrict__ z2,
    const int* __restrict__ SET0, const int* __restrict__ L0LEN) {
  int g = blockIdx.x * 256 + threadIdx.x;  // exact grid: 2*8*992*40
  int c = g % 40;
  int t2 = g / 40;
  int rr = t2 % 992;
  int bzi = t2 / 992;
  int b = bzi & 7;
  unsigned short* z = (bzi >> 3) ? z2 : z1;
  int l, j, off0;
  if (rr < 512)      { l = 1; j = rr;       off0 = 0; }
  else if (rr < 768) { l = 2; j = rr - 512; off0 = 512; }
  else if (rr < 896) { l = 3; j = rr - 768; off0 = 768; }
  else if (rr < 960) { l = 4; j = rr - 896; off0 = 896; }
  else               { l = 5; j = rr - 960; off0 = 960; }
  int len = L0LEN[b * 992 + off0 + j];
  const int* st = SET0 + b * 5120 + (l - 1) * 1024 + (j << l);
  const unsigned short* src = z + (size_t)b * 1024 * D_DIM;
  int cc = c * 8;
  bf16x8_t mx = *(const bf16x8_t*)(src + (size_t)st[0] * D_DIM + cc);
  for (int e = 1; e < len; ++e) {
    bf16x8_t a = *(const bf16x8_t*)(src + (size_t)st[e] * D_DIM + cc);
#pragma unroll
    for (int q = 0; q < 8; ++q)
      mx[q] = (bf2f((unsigned short)mx[q]) >= bf2f((unsigned short)a[q])) ? mx[q] : a[q];
  }
  size_t zo = (size_t)2560 * (2048 - (2048 >> l));
  int Tl = 1024 >> l;
  *(bf16x8_t*)(z + zo + ((size_t)b * Tl + j) * D_DIM + cc) = mx;
}

// ---------------- work45: [408 L1-5 tiles] + [78 mat2] + [248 L1-5 inst] -----
__global__ __launch_bounds__(256, 3) void work45_kernel(
    unsigned short* __restrict__ z1, unsigned short* __restrict__ z2,
    const int* __restrict__ SET5, const int* __restrict__ L5LEN,
    float* __restrict__ wsm, float* __restrict__ wss,
    float* __restrict__ wsInst, Tab tab) {
  __shared__ __align__(16) unsigned char smem[49152];
  int bx = blockIdx.x;
  int tid = threadIdx.x;

  if (bx < 408) {
    // ========== levels 1..5 temporal tiles ==========
    int g = tab.tileStart[1] + bx;
    int l = 1;
    while (g >= tab.tileStart[l + 1]) ++l;
    int T = tab.T[l], S = tab.S[l];
    int local = g - tab.tileStart[l];
    int npl = (S * (S + 1)) >> 1;
    int nid = (local % 8) * npl + local / 8;
    int b = nid / npl;
    int pr = nid % npl;
    int rb = 0, tt = pr;
    while (tt >= S - rb) { tt -= S - rb; ++rb; }
    int sg = rb + tt;
    tile_body(smem, tid, z1 + tab.zoff[l], z2 + tab.zoff[l], b, T, S, rb, sg,
              wsm + tab.wsoff[l], wss + tab.wsoff[l]);
  } else if (bx < 486) {
    // ========== mat2: levels 6..10 from level-5 origin sets ==========
    int g = (bx - 408) * 256 + tid;
    if (g >= 2 * 8 * 31 * 40) return;
    int c = g % 40;
    int t2 = g / 40;
    int rr = t2 % 31;
    int bzi = t2 / 31;
    int b = bzi & 7;
    unsigned short* z = (bzi >> 3) ? z2 : z1;
    int l, j, off5;
    if (rr < 16)      { l = 6;  j = rr;      off5 = 0; }
    else if (rr < 24) { l = 7;  j = rr - 16; off5 = 16; }
    else if (rr < 28) { l = 8;  j = rr - 24; off5 = 24; }
    else if (rr < 30) { l = 9;  j = rr - 28; off5 = 28; }
    else              { l = 10; j = rr - 30; off5 = 30; }
    int len = L5LEN[b * 32 + off5 + j];
    const int* st = SET5 + b * 160 + (l - 6) * 32 + (j << (l - 5));
    const unsigned short* src = z + (size_t)2560 * (2048 - 64) + (size_t)b * 32 * D_DIM;
    int cc = c * 8;
    bf16x8_t mx = *(const bf16x8_t*)(src + (size_t)st[0] * D_DIM + cc);
    for (int e = 1; e < len; ++e) {
      bf16x8_t a = *(const bf16x8_t*)(src + (size_t)st[e] * D_DIM + cc);
#pragma unroll
      for (int q = 0; q < 8; ++q)
        mx[q] = (bf2f((unsigned short)mx[q]) >= bf2f((unsigned short)a[q])) ? mx[q] : a[q];
    }
    size_t zo = (size_t)2560 * (2048 - (2048 >> l));
    int Tl = 1024 >> l;
    *(bf16x8_t*)(z + zo + ((size_t)b * Tl + j) * D_DIM + cc) = mx;
  } else {
    // ========== levels 1..5 instance ==========
    int iw = 1024 + (bx - 486) * 4 + (tid >> 6);
    if (iw < 2016) {
      int l = 1;
      while (iw >= tab.instStart[l + 1]) ++l;
      int t = iw - tab.instStart[l];
      float lsum = inst_wave(z1 + tab.zoff[l], z2 + tab.zoff[l], tab.T[l], t,
                             tid & 63);
      if ((tid & 63) == 0) wsInst[iw] = lsum * tab.scale[l];
    }
  }
}

// ---------------- final: combine + tiny temporal (6-9) + inst 6-10 ----------
__global__ __launch_bounds__(256) void final_kernel(
    const unsigned short* __restrict__ z1, const unsigned short* __restrict__ z2,
    const float* __restrict__ wsm, const float* __restrict__ wss,
    const float* __restrict__ wsInst, float* __restrict__ out, Tab tab,
    int nc) {
  int bx = blockIdx.x;
  int tid = threadIdx.x;

  if (bx < nc) {
    int g = bx * 256 + tid;
    float loss = 0.f;
    if (g < tab.totr) {
      int l = 0;
      while (g >= tab.rstart[l + 1]) ++l;
      int row = g - tab.rstart[l];
      int T = tab.T[l], N = 2 * T, S = tab.S[l];
      int b = row / N, r = row % N;
      const float* wm = wsm + tab.wsoff[l];
      const float* wv = wss + tab.wsoff[l];
      float m = NEGINF;
      for (int s = 0; s < S; ++s) m = fmaxf(m, wm[(b * S + s) * N + r]);
      float sv = 0.f;
      for (int s = 0; s < S; ++s) {
        int idx = (b * S + s) * N + r;
        sv += wv[idx] * __expf(wm[idx] - m);
      }
      const unsigned short* zz1 = z1 + tab.zoff[l];
      const unsigned short* zz2 = z2 + tab.zoff[l];
      int pos = (r < T) ? r + T : r - T;
      const bf16x8_t* za = (const bf16x8_t*)zrowb(zz1, zz2, b, T, r);
      const bf16x8_t* zp = (const bf16x8_t*)zrowb(zz1, zz2, b, T, pos);
      float dot = 0.f;
      for (int k = 0; k < D_DIM / 8; ++k) {
        bf16x8_t a = za[k], p = zp[k];
#pragma unroll
        for (int e = 0; e < 8; ++e)
          dot += bf2f((unsigned short)a[e]) * bf2f((unsigned short)p[e]);
      }
      loss = (m + logf(sv) - dot) * tab.scale[l];
    } else if (g < tab.totr + 2016) {
      loss = wsInst[g - tab.totr];
    }
    float v = loss;
#pragma unroll
    for (int o = 1; o < 64; o <<= 1) v += __shfl_xor(v, o);
    __shared__ float part[4];
    int w = tid >> 6;
    if ((tid & 63) == 0) part[w] = v;
    __syncthreads();
    if (tid == 0)
      atomicAdd(out, part[0] + part[1] + part[2] + part[3]);
  } else if (bx < nc + 8) {
    // ---- tiny temporal levels 6..9: one wave per (b, l), 32x32 MFMA ----
    int widx = (bx - nc) * 4 + (tid >> 6);
    int l = 6 + (widx >> 3), b = widx & 7;
    int T = tab.T[l], N = 2 * T;
    const unsigned short* zz1 = z1 + tab.zoff[l];
    const unsigned short* zz2 = z2 + tab.zoff[l];
    int lane = tid & 63;
    int col = lane & 31, h = lane >> 5;
    int rl = (col < N) ? col : 0;
    const unsigned short* rowp = (rl < T)
        ? zz1 + ((size_t)b * T + rl) * D_DIM
        : zz2 + ((size_t)b * T + (rl - T)) * D_DIM;
    rowp += h * 8;
    f32x16_t acc = (f32x16_t)(0.f);
#pragma unroll
    for (int m2 = 0; m2 < 20; ++m2) {
      bf16x8_t a = *(const bf16x8_t*)(rowp + m2 * 16);
      acc = __builtin_amdgcn_mfma_f32_32x32x16_bf16(a, a, acc, 0, 0, 0);
    }
    float lsum = 0.f;
#pragma unroll
    for (int rg = 0; rg < 16; ++rg) {
      int row = (rg & 3) + 8 * (rg >> 2) + 4 * h;
      float x = acc[rg];
      float xm = (col < N && row < N && col != row) ? x : NEGINF;
      float m = xm;
#pragma unroll
      for (int o = 1; o < 32; o <<= 1) m = fmaxf(m, __shfl_xor(m, o));
      float s = __expf(xm - m);
#pragma unroll
      for (int o = 1; o < 32; o <<= 1) s += __shfl_xor(s, o);
      int pos = (row < T) ? row + T : row - T;
      if (row < N && col == pos) lsum += m + __logf(s) - x;
    }
#pragma unroll
    for (int o = 1; o < 64; o <<= 1) lsum += __shfl_xor(lsum, o);
    if (lane == 0) atomicAdd(out, lsum * tab.scale[l]);
  } else {
    // ---- instance levels 6..10: one wave per t, direct atomic ----
    int widx = (bx - nc - 8) * 4 + (tid >> 6);
    if (widx < 31) {
      int iw = 2016 + widx;
      int l = 6;
      while (iw >= tab.instStart[l + 1]) ++l;
      int t = iw - tab.instStart[l];
      float lsum = inst_wave(z1 + tab.zoff[l], z2 + tab.zoff[l], tab.T[l], t,
                             tid & 63);
      if ((tid & 63) == 0) atomicAdd(out, lsum * tab.scale[l]);
    }
  }
}

extern "C" void kernel_launch(void* const* d_in, const int* in_sizes, int n_in,
                              void* d_out, int out_size, void* d_ws, size_t ws_size,
                              hipStream_t stream) {
  const float* z1_in = (const float*)d_in[0];
  const float* z2_in = (const float*)d_in[1];
  const int* time_in = (const int*)d_in[2];
  float* out = (float*)d_out;

  // ---- level tables ----
  Tab tab;
  int zo = 0, wso = 0, ts = 0, is = 0, rs = 0;
  for (int l = 0; l < 11; ++l) {
    int T = 1024 >> l, N = 2 * T;
    int S = (N >= 128) ? N / 128 : 1;
    tab.T[l] = T;
    tab.S[l] = S;
    tab.zoff[l] = zo;
    tab.scale[l] = 1.0f / (352.0f * (float)T);  // 0.5/(2*B*T)/11
    tab.tileStart[l] = ts;
    tab.instStart[l] = is;
    tab.wsoff[l] = (T > 1) ? wso : 0;
    tab.rstart[l] = rs;
    if (T > 1) {
      ts += 8 * ((S * (S + 1)) >> 1);
      wso += 8 * S * N;
      if (l <= 5) rs += 8 * N;   // combine covers temporal rows of levels 0..5
    }
    is += T;
    zo += 8 * T * D_DIM;
  }
  tab.tileStart[11] = ts;
  tab.instStart[11] = is;
  for (int l = 6; l <= 11; ++l) tab.rstart[l] = rs;
  tab.totTemp = ts;
  tab.totInst = is;
  tab.totr = rs;

  // ---- workspace carve ----
  char* w = (char*)d_ws;
  unsigned short* z1s = (unsigned short*)w; w += (size_t)zo * 2;
  unsigned short* z2s = (unsigned short*)w; w += (size_t)zo * 2;
  float* wsm = (float*)w; w += (size_t)wso * sizeof(float);
  float* wss = (float*)w; w += (size_t)wso * sizeof(float);
  float* wsInst = (float*)w; w += (size_t)is * sizeof(float);
  int* SET0 = (int*)w; w += (size_t)8 * 5120 * sizeof(int);
  int* L0LEN = (int*)w; w += (size_t)8 * 992 * sizeof(int);
  int* SET5 = (int*)w; w += (size_t)8 * 160 * sizeof(int);
  int* L5LEN = (int*)w; w += (size_t)8 * 32 * sizeof(int);

  int n0 = 8 * 1024 * D_DIM;
  convert_kernel<<<2048, 256, 0, stream>>>(z1_in, z2_in, z1s, z2s, n0 / 4,
                                           out, out_size);
  work0_kernel<<<8 + 1088 + 256, 256, 0, stream>>>(
      time_in, z1s, z2s, wsm, wss, wsInst, SET0, L0LEN, SET5, L5LEN);
  mat1_kernel<<<2480, 256, 0, stream>>>(z1s, z2s, SET0, L0LEN);
  work45_kernel<<<408 + 78 + 248, 256, 0, stream>>>(
      z1s, z2s, SET5, L5LEN, wsm, wss, wsInst, tab);
  int nc = (tab.totr + 2016 + 255) / 256;
  final_kernel<<<nc + 16, 256, 0, stream>>>(z1s, z2s, wsm, wss, wsInst, out,
                                            tab, nc);
}

// Round 18
// 104.027 us; speedup vs baseline: 1.2839x; 1.1266x over previous
//
#include <hip/hip_runtime.h>
#include <cstdint>
#include <cstddef>

#define D_DIM 320
#define NEGINF (-1e30f)

typedef __attribute__((ext_vector_type(8))) short bf16x8_t;
typedef __attribute__((ext_vector_type(4))) float f32x4_t;
typedef __attribute__((ext_vector_type(16))) float f32x16_t;

struct Tab {
  int T[11], S[11], zoff[11], wsoff[11];
  int tileStart[12], instStart[12], rstart[12];
  float scale[11];
  int totTemp, totInst, totr;
};

__device__ __forceinline__ float bf2f(unsigned short u) {
  union { unsigned int i; float f; } v; v.i = ((unsigned int)u) << 16; return v.f;
}
__device__ __forceinline__ unsigned short f2bf(float f) {
  union { float f; unsigned int i; } u; u.f = f;
  unsigned int b = u.i + 0x7FFFu + ((u.i >> 16) & 1u);
  return (unsigned short)(b >> 16);
}

__device__ __forceinline__ const unsigned short* zrowb(
    const unsigned short* __restrict__ z1, const unsigned short* __restrict__ z2,
    int b, int T, int r) {
  return (r < T) ? (z1 + ((size_t)b * T + r) * D_DIM)
                 : (z2 + ((size_t)b * T + (r - T)) * D_DIM);
}

#define GLOAD_LDS16(SRC, DST)                                                   \
  __builtin_amdgcn_global_load_lds(                                             \
      (const __attribute__((address_space(1))) void*)(SRC),                     \
      (__attribute__((address_space(3))) void*)(DST), 16, 0, 0)

// ---- ring-3 tile-engine macros: buffers at short-offsets 0/8192/16384 ----
#define BUF1 8192
#define BUF2 16384

#define STAGE(koff, bufofs)                                                     \
    do {                                                                        \
      GLOAD_LDS16(gA0 + (koff), dA0 + (bufofs));                                \
      GLOAD_LDS16(gA1 + (koff), dA1 + (bufofs));                                \
      GLOAD_LDS16(gB0 + (koff), dB0 + (bufofs));                                \
      GLOAD_LDS16(gB1 + (koff), dB1 + (bufofs));                                \
    } while (0)

#define PHASE3(k, bo, bo2, VM, DO_PF)                                           \
    do {                                                                        \
      asm volatile("s_waitcnt vmcnt(" #VM ")" ::: "memory");                    \
      __builtin_amdgcn_s_barrier();                                             \
      if (DO_PF) STAGE((k + 2) * 32, bo2);                                      \
      bf16x8_t af[4], bfr[4];                                                   \
      _Pragma("unroll")                                                         \
      for (int at = 0; at < 4; ++at)                                            \
        af[at] = *(const bf16x8_t*)(vA + (bo) + at * 128);                      \
      _Pragma("unroll")                                                         \
      for (int ct = 0; ct < 4; ++ct)                                            \
        bfr[ct] = *(const bf16x8_t*)(vB + (bo) + ct * 128);                     \
      asm volatile("s_waitcnt lgkmcnt(0)" ::: "memory");                        \
      __builtin_amdgcn_sched_barrier(0);                                        \
      __builtin_amdgcn_s_setprio(1);                                            \
      _Pragma("unroll")                                                         \
      for (int ct = 0; ct < 4; ++ct)                                            \
        _Pragma("unroll")                                                       \
        for (int at = 0; at < 4; ++at)                                          \
          acc[at][ct] = __builtin_amdgcn_mfma_f32_16x16x32_bf16(                \
              af[at], bfr[ct], acc[at][ct], 0, 0, 0);                           \
      __builtin_amdgcn_s_setprio(0);                                            \
    } while (0)

// ================= shared device helpers =================
// 128x128 tile; per-row LSE partials + positive-pair harvest into wp
__device__ __forceinline__ void tile_body(
    unsigned char* smem, int tid,
    const unsigned short* zz1, const unsigned short* zz2,
    int b, int T, int S, int rb, int sg,
    float* wm, float* wv, float* wp) {
  int N = 2 * T;
  int row0 = rb * 128, col0 = sg * 128;
  int w = tid >> 6, lane = tid & 63;
  int lq = lane >> 4, lr = lane & 15;
  int wr = w >> 1, wc = w & 1;

  unsigned short* lds = (unsigned short*)smem;

  int ra0 = row0 + lane;        if (ra0 > N - 1) ra0 = N - 1;
  int ra1 = row0 + 64 + lane;   if (ra1 > N - 1) ra1 = N - 1;
  int ca0 = col0 + lane;        if (ca0 > N - 1) ca0 = N - 1;
  int ca1 = col0 + 64 + lane;   if (ca1 > N - 1) ca1 = N - 1;
  const unsigned short* gA0 = zrowb(zz1, zz2, b, T, ra0) + w * 8;
  const unsigned short* gA1 = zrowb(zz1, zz2, b, T, ra1) + w * 8;
  const unsigned short* gB0 = zrowb(zz1, zz2, b, T, ca0) + w * 8;
  const unsigned short* gB1 = zrowb(zz1, zz2, b, T, ca1) + w * 8;
  unsigned short* dA0 = &lds[((w) * 128 + lane) * 8];
  unsigned short* dA1 = &lds[((w) * 128 + 64 + lane) * 8];
  unsigned short* dB0 = &lds[((4 + w) * 128 + lane) * 8];
  unsigned short* dB1 = &lds[((4 + w) * 128 + 64 + lane) * 8];

  f32x4_t acc[4][4];
#pragma unroll
  for (int at = 0; at < 4; ++at)
#pragma unroll
    for (int ct = 0; ct < 4; ++ct) acc[at][ct] = (f32x4_t)(0.f);

  const unsigned short* vA = &lds[((lq) * 128 + wr * 64 + lr) * 8];
  const unsigned short* vB = &lds[((4 + lq) * 128 + wc * 64 + lr) * 8];

  STAGE(0, 0);
  STAGE(32, BUF1);
  PHASE3(0, 0,    BUF2, 4, 1);
  PHASE3(1, BUF1, 0,    4, 1);
  PHASE3(2, BUF2, BUF1, 4, 1);
  PHASE3(3, 0,    BUF2, 4, 1);
  PHASE3(4, BUF1, 0,    4, 1);
  PHASE3(5, BUF2, BUF1, 4, 1);
  PHASE3(6, 0,    BUF2, 4, 1);
  PHASE3(7, BUF1, 0,    4, 1);
  PHASE3(8, BUF2, 0,    4, 0);
  PHASE3(9, 0,    0,    0, 0);
  __builtin_amdgcn_s_barrier();  // staging dead; alias epilogue into buffer0

  float (*mS)[128] = (float(*)[128])(smem);
  float (*sS)[128] = (float(*)[128])(smem + 1024);
  float (*mC)[128] = (float(*)[128])(smem + 2048);
  float (*sC)[128] = (float(*)[128])(smem + 3072);

  // row-LSE -> partial (col-seg sg); harvest positive-pair sims
#pragma unroll
  for (int at = 0; at < 4; ++at) {
#pragma unroll
    for (int rg = 0; rg < 4; ++rg) {
      int rloc = wr * 64 + at * 16 + lq * 4 + rg;
      int rglob = row0 + rloc;
      int posr = (rglob < T) ? rglob + T : rglob - T;
      float v[4];
#pragma unroll
      for (int ct = 0; ct < 4; ++ct) {
        int cg = col0 + wc * 64 + ct * 16 + lr;
        float val = acc[at][ct][rg];
        if (rglob < N && cg == posr) {
          wp[b * N + rglob] = val;
          wp[b * N + cg] = val;
        }
        v[ct] = (cg < N && cg != rglob) ? val : NEGINF;
      }
      float m = fmaxf(fmaxf(v[0], v[1]), fmaxf(v[2], v[3]));
#pragma unroll
      for (int o = 1; o < 16; o <<= 1) m = fmaxf(m, __shfl_xor(m, o));
      float sv = __expf(v[0] - m) + __expf(v[1] - m) +
                 __expf(v[2] - m) + __expf(v[3] - m);
#pragma unroll
      for (int o = 1; o < 16; o <<= 1) sv += __shfl_xor(sv, o);
      if (lr == 0) { mS[wc][rloc] = m; sS[wc][rloc] = sv; }
    }
  }
  // col-LSE (symmetry) -> partial (col-seg rb); off-diag tiles only
  if (rb != sg) {
#pragma unroll
    for (int ct = 0; ct < 4; ++ct) {
      float m = NEGINF;
#pragma unroll
      for (int at = 0; at < 4; ++at)
#pragma unroll
        for (int rg = 0; rg < 4; ++rg) m = fmaxf(m, acc[at][ct][rg]);
      m = fmaxf(m, __shfl_xor(m, 16));
      m = fmaxf(m, __shfl_xor(m, 32));
      float s = 0.f;
#pragma unroll
      for (int at = 0; at < 4; ++at)
#pragma unroll
        for (int rg = 0; rg < 4; ++rg) s += __expf(acc[at][ct][rg] - m);
      s += __shfl_xor(s, 16);
      s += __shfl_xor(s, 32);
      if (lq == 0) {
        mC[wr][wc * 64 + ct * 16 + lr] = m;
        sC[wr][wc * 64 + ct * 16 + lr] = s;
      }
    }
  }
  __syncthreads();

  if (tid < 128) {
    int rglob = row0 + tid;
    if (rglob < N) {
      float m0 = mS[0][tid], m1 = mS[1][tid];
      float m = fmaxf(m0, m1);
      float sv = sS[0][tid] * __expf(m0 - m) + sS[1][tid] * __expf(m1 - m);
      int idx = (b * S + sg) * N + rglob;
      wm[idx] = m;
      wv[idx] = sv;
    }
    if (rb != sg) {
      float m0 = mC[0][tid], m1 = mC[1][tid];
      float m = fmaxf(m0, m1);
      float sv = sC[0][tid] * __expf(m0 - m) + sC[1][tid] * __expf(m1 - m);
      int idx = (b * S + rb) * N + col0 + tid;
      wm[idx] = m;
      wv[idx] = sv;
    }
  }
}

// instance (16x16, one wave per t): returns wave loss sum (valid at lane 0)
__device__ __forceinline__ float inst_wave(
    const unsigned short* zz1, const unsigned short* zz2, int T, int t, int lane) {
  int lq = lane >> 4, lr = lane & 15;
  const unsigned short* zr = (lr < 8)
      ? zz1 + ((size_t)lr * T + t) * D_DIM
      : zz2 + ((size_t)(lr - 8) * T + t) * D_DIM;
  zr += lq * 8;
  f32x4_t c = (f32x4_t)(0.f);
#pragma unroll
  for (int k = 0; k < 10; ++k) {
    bf16x8_t a = *(const bf16x8_t*)(zr + k * 32);
    c = __builtin_amdgcn_mfma_f32_16x16x32_bf16(a, a, c, 0, 0, 0);
  }
  float lsum = 0.f;
#pragma unroll
  for (int rg = 0; rg < 4; ++rg) {
    int rrow = lq * 4 + rg;
    float v = c[rg];
    float x = (lr != rrow) ? v : NEGINF;
    float m = x;
#pragma unroll
    for (int o = 1; o < 16; o <<= 1) m = fmaxf(m, __shfl_xor(m, o));
    float s = __expf(x - m);
#pragma unroll
    for (int o = 1; o < 16; o <<= 1) s += __shfl_xor(s, o);
    int pos = (rrow < 8) ? rrow + 8 : rrow - 8;
    if (lr == pos) lsum += m + __logf(s) - v;
  }
#pragma unroll
  for (int o = 1; o < 64; o <<= 1) lsum += __shfl_xor(lsum, o);
  return lsum;
}

// ---------------- convert: fp32 -> bf16 + zero out ----------------
__global__ __launch_bounds__(256) void convert_kernel(
    const float* __restrict__ i1, const float* __restrict__ i2,
    unsigned short* __restrict__ o1, unsigned short* __restrict__ o2,
    int n4, float* __restrict__ out, int outn) {
  int i = blockIdx.x * 256 + threadIdx.x;
  if (i < outn) out[i] = 0.f;
  int stride = gridDim.x * 256;
  for (int j = i; j < n4; j += stride) {
    float4 v = ((const float4*)i1)[j];
    ushort4 r;
    r.x = f2bf(v.x); r.y = f2bf(v.y); r.z = f2bf(v.z); r.w = f2bf(v.w);
    ((ushort4*)o1)[j] = r;
    float4 u = ((const float4*)i2)[j];
    ushort4 q;
    q.x = f2bf(u.x); q.y = f2bf(u.y); q.z = f2bf(u.z); q.w = f2bf(u.w);
    ((ushort4*)o2)[j] = q;
  }
}

// ---------------- work0: [8 sort blocks] + [1088 L0 tiles] + [256 L0 inst] ---
__global__ __launch_bounds__(256, 3) void work0_kernel(
    const int* __restrict__ time0,
    const unsigned short* __restrict__ z1, const unsigned short* __restrict__ z2,
    float* __restrict__ wsm, float* __restrict__ wss, float* __restrict__ wpos,
    float* __restrict__ wsInst,
    int* __restrict__ SET0, int* __restrict__ L0LEN,
    int* __restrict__ SET5, int* __restrict__ L5LEN) {
  __shared__ __align__(16) unsigned char smem[49152];
  int bx = blockIdx.x;
  int tid = threadIdx.x;

  if (bx < 8) {
    // ===== bucket-rank stable argsort (2048 bins) + origin-set expansion =====
    int b = bx;
    int lane = tid & 63, wid = tid >> 6;
    int* tcur = (int*)smem;                                    // 4096
    unsigned* hist = (unsigned*)(smem + 4096);                 // 8192 (2048 u32)
    unsigned short* cum = (unsigned short*)(smem + 12288);     // 4096 (2048 u16)
    unsigned long long* arr = (unsigned long long*)(smem + 16384);  // 8192
    int* sortedIdx = (int*)(smem + 24576);                     // 4096
    int* tnew = (int*)(smem + 28672);                          // 2048
    int* srcK = (int*)(smem + 30720);                          // 2048
    int* setA = (int*)(smem + 32768);                          // 4096
    int* setB = (int*)(smem + 36864);                          // 4096
    int* lenA = (int*)(smem + 40960);                          // 4096
    int* lenB = (int*)(smem + 45056);                          // 2048
    unsigned* minW = (unsigned*)(smem + 47104);
    unsigned* maxW = (unsigned*)(smem + 47168);
    unsigned* wsum = (unsigned*)(smem + 47232);
    int* wcnt = (int*)(smem + 47296);

#pragma unroll
    for (int i = 0; i < 4; ++i) {
      int e = tid + 256 * i;
      tcur[e] = time0[b * 1024 + e];
      setA[e] = e;
      lenA[e] = 1;
    }
    __syncthreads();

    int pp = 0;
    for (int lvl = 1; lvl <= 10; ++lvl) {
      int T = 2048 >> lvl;
      int n = T - 1, half = T >> 1;
      bool act[4];
      int dd[4];
      unsigned bkey[4];
      unsigned mn = 0xFFFFFFFFu, mx = 0u;
#pragma unroll
      for (int i = 0; i < 4; ++i) {
        int e = tid + 256 * i;
        act[i] = e < n;
        dd[i] = 0; bkey[i] = 0;
        if (act[i]) {
          dd[i] = tcur[e + 1] - tcur[e];
          bkey[i] = __float_as_uint((float)dd[i]);
          mn = mn < bkey[i] ? mn : bkey[i];
          mx = mx > bkey[i] ? mx : bkey[i];
        }
        hist[e] = 0;
        hist[e + 1024] = 0;
      }
#pragma unroll
      for (int o = 1; o < 64; o <<= 1) {
        unsigned m2 = (unsigned)__shfl_xor((int)mn, o);
        unsigned x2 = (unsigned)__shfl_xor((int)mx, o);
        mn = mn < m2 ? mn : m2;
        mx = mx > x2 ? mx : x2;
      }
      if (lane == 0) { minW[wid] = mn; maxW[wid] = mx; }
      __syncthreads();

      unsigned bmin = 0xFFFFFFFFu, bmax = 0;
#pragma unroll
      for (int i = 0; i < 4; ++i) {
        bmin = bmin < minW[i] ? bmin : minW[i];
        bmax = bmax > maxW[i] ? bmax : maxW[i];
      }
      unsigned long long range = (unsigned long long)(bmax - bmin) + 1;
      unsigned long long scl = (2048ULL << 30) / range;
      int bkt[4]; unsigned av[4];
#pragma unroll
      for (int i = 0; i < 4; ++i) {
        if (act[i]) {
          int bk = (int)(((unsigned long long)(bkey[i] - bmin) * scl) >> 30);
          bkt[i] = bk > 2047 ? 2047 : bk;
          av[i] = atomicAdd(&hist[bkt[i]], 1u);
        }
      }
      __syncthreads();

      {  // exclusive scan over 2048 bins: 8 bins/thread
        unsigned lv[8];
        unsigned s = 0;
#pragma unroll
        for (int j = 0; j < 8; ++j) { lv[j] = hist[8 * tid + j]; s += lv[j]; }
        unsigned inc = s;
#pragma unroll
        for (int o = 1; o < 64; o <<= 1) {
          unsigned t = (unsigned)__shfl_up((int)inc, o);
          if (lane >= o) inc += t;
        }
        if (lane == 63) wsum[wid] = inc;
        __syncthreads();
        unsigned wpre = 0;
        for (int j = 0; j < wid; ++j) wpre += wsum[j];
        unsigned ex = wpre + inc - s;
#pragma unroll
        for (int j = 0; j < 8; ++j) { cum[8 * tid + j] = (unsigned short)ex; ex += lv[j]; }
      }
      __syncthreads();

      unsigned long long key[4];
      int base[4], occ[4];
#pragma unroll
      for (int i = 0; i < 4; ++i) {
        base[i] = 0; occ[i] = 0;
        if (act[i]) {
          key[i] = ((unsigned long long)(unsigned)dd[i] << 10) |
                   (unsigned)(tid + 256 * i);
          base[i] = (int)cum[bkt[i]];
          arr[base[i] + av[i]] = key[i];
        }
      }
      __syncthreads();

      // interleaved 4-wide within-bucket rank count (latency-hidden)
      int cnt[4] = {0, 0, 0, 0};
      int mocc = 0;
#pragma unroll
      for (int i = 0; i < 4; ++i) {
        if (act[i]) {
          occ[i] = (int)hist[bkt[i]];
          mocc = occ[i] > mocc ? occ[i] : mocc;
        }
      }
      for (int j = 0; j < mocc; ++j) {
#pragma unroll
        for (int i = 0; i < 4; ++i)
          if (j < occ[i]) cnt[i] += (arr[base[i] + j] < key[i]) ? 1 : 0;
      }
#pragma unroll
      for (int i = 0; i < 4; ++i)
        if (act[i]) sortedIdx[base[i] + cnt[i]] = tid + 256 * i;
      __syncthreads();

      bool msk[4]; int rw[4];
#pragma unroll
      for (int i = 0; i < 4; ++i) {
        int k = tid + 256 * i;
        msk[i] = (k < n) && (sortedIdx[k] < half);
        unsigned long long bal = __ballot(msk[i]);
        rw[i] = __popcll(bal & ((1ull << lane) - 1ull));
        if (lane == 0) wcnt[i * 4 + wid] = (int)__popcll(bal);
      }
      __syncthreads();
#pragma unroll
      for (int i = 0; i < 4; ++i) {
        if (msk[i]) {
          int seg = i * 4 + wid;
          int pre = 0;
          for (int j = 0; j < seg; ++j) pre += wcnt[j];
          int rr = pre + rw[i];
          int k = tid + 256 * i;
          srcK[rr] = k;
          tnew[rr] = (tcur[k] + tcur[k + 1]) >> 1;
        }
      }
      __syncthreads();

      if (lvl == 6) {
        int* sp = pp ? setB : setA;
        int* lp = pp ? lenB : lenA;
        if (tid < 32) { sp[tid] = tid; lp[tid] = 1; }
        __syncthreads();
      }
      {
        int ll = (lvl <= 5) ? lvl : (lvl - 5);
        int* sp = pp ? setB : setA;
        int* lp = pp ? lenB : lenA;
        int* sc = pp ? setA : setB;
        int* lc = pp ? lenA : lenB;
        int *gset, *glen;
        if (lvl <= 5) {
          gset = SET0 + b * 5120 + (lvl - 1) * 1024;
          glen = L0LEN + b * 992 + (1024 - (1024 >> (lvl - 1)));
        } else {
          gset = SET5 + b * 160 + (lvl - 6) * 32;
          glen = L5LEN + b * 32 + (32 - (32 >> (lvl - 6)));
        }
        int tmax = half << ll;
#pragma unroll
        for (int i = 0; i < 4; ++i) {
          int s = tid + 256 * i;
          if (s < tmax) {
            int j = s >> ll, e2 = s & ((1 << ll) - 1);
            int k = srcK[j];
            int la = lp[k], lb2 = lp[k + 1];
            int v = -1;
            int sh = ll - 1;
            if (e2 < la) v = sp[(k << sh) + e2];
            else if (e2 < la + lb2) v = sp[((k + 1) << sh) + (e2 - la)];
            if (e2 == 0) { lc[j] = la + lb2; glen[j] = la + lb2; }
            if (v >= 0) { sc[s] = v; gset[s] = v; }
          }
        }
        __syncthreads();
        pp ^= 1;
      }
#pragma unroll
      for (int i = 0; i < 4; ++i) {
        int j = tid + 256 * i;
        if (j < half) tcur[j] = tnew[j];
      }
      __syncthreads();
    }
  } else if (bx < 8 + 1088) {
    // ========== level-0 temporal tile (rb<=sg) ==========
    const int T = 1024, S = 16;
    int local = bx - 8;
    int b = local % 8;
    int pr = local / 8;
    int rb = 0, tt = pr;
    while (tt >= S - rb) { tt -= S - rb; ++rb; }
    int sg = rb + tt;
    tile_body(smem, tid, z1, z2, b, T, S, rb, sg, wsm, wss, wpos);
  } else {
    // ========== level-0 instance: one wave per t ==========
    int iw = (bx - 1096) * 4 + (tid >> 6);
    float lsum = inst_wave(z1, z2, 1024, iw, tid & 63);
    if ((tid & 63) == 0) wsInst[iw] = lsum * (1.0f / 360448.0f);
  }
}

// ---------------- mat1: z levels 1..5 = max over level-0 origin sets ---------
__global__ __launch_bounds__(256) void mat1_kernel(
    unsigned short* __restrict__ z1, unsigned short* __restrict__ z2,
    const int* __restrict__ SET0, const int* __restrict__ L0LEN) {
  int g = blockIdx.x * 256 + threadIdx.x;  // exact grid: 2*8*992*40
  int c = g % 40;
  int t2 = g / 40;
  int rr = t2 % 992;
  int bzi = t2 / 992;
  int b = bzi & 7;
  unsigned short* z = (bzi >> 3) ? z2 : z1;
  int l, j, off0;
  if (rr < 512)      { l = 1; j = rr;       off0 = 0; }
  else if (rr < 768) { l = 2; j = rr - 512; off0 = 512; }
  else if (rr < 896) { l = 3; j = rr - 768; off0 = 768; }
  else if (rr < 960) { l = 4; j = rr - 896; off0 = 896; }
  else               { l = 5; j = rr - 960; off0 = 960; }
  int len = L0LEN[b * 992 + off0 + j];
  const int* st = SET0 + b * 5120 + (l - 1) * 1024 + (j << l);
  const unsigned short* src = z + (size_t)b * 1024 * D_DIM;
  int cc = c * 8;
  bf16x8_t mx = *(const bf16x8_t*)(src + (size_t)st[0] * D_DIM + cc);
  for (int e = 1; e < len; ++e) {
    bf16x8_t a = *(const bf16x8_t*)(src + (size_t)st[e] * D_DIM + cc);
#pragma unroll
    for (int q = 0; q < 8; ++q)
      mx[q] = (bf2f((unsigned short)mx[q]) >= bf2f((unsigned short)a[q])) ? mx[q] : a[q];
  }
  size_t zo = (size_t)2560 * (2048 - (2048 >> l));
  int Tl = 1024 >> l;
  *(bf16x8_t*)(z + zo + ((size_t)b * Tl + j) * D_DIM + cc) = mx;
}

// ---------------- work45: [408 L1-5 tiles] + [78 mat2] + [248 L1-5 inst] -----
__global__ __launch_bounds__(256, 3) void work45_kernel(
    unsigned short* __restrict__ z1, unsigned short* __restrict__ z2,
    const int* __restrict__ SET5, const int* __restrict__ L5LEN,
    float* __restrict__ wsm, float* __restrict__ wss, float* __restrict__ wpos,
    float* __restrict__ wsInst, Tab tab) {
  __shared__ __align__(16) unsigned char smem[49152];
  int bx = blockIdx.x;
  int tid = threadIdx.x;

  if (bx < 408) {
    // ========== levels 1..5 temporal tiles ==========
    int g = tab.tileStart[1] + bx;
    int l = 1;
    while (g >= tab.tileStart[l + 1]) ++l;
    int T = tab.T[l], S = tab.S[l];
    int local = g - tab.tileStart[l];
    int npl = (S * (S + 1)) >> 1;
    int nid = (local % 8) * npl + local / 8;
    int b = nid / npl;
    int pr = nid % npl;
    int rb = 0, tt = pr;
    while (tt >= S - rb) { tt -= S - rb; ++rb; }
    int sg = rb + tt;
    tile_body(smem, tid, z1 + tab.zoff[l], z2 + tab.zoff[l], b, T, S, rb, sg,
              wsm + tab.wsoff[l], wss + tab.wsoff[l], wpos + tab.rstart[l]);
  } else if (bx < 486) {
    // ========== mat2: levels 6..10 from level-5 origin sets ==========
    int g = (bx - 408) * 256 + tid;
    if (g >= 2 * 8 * 31 * 40) return;
    int c = g % 40;
    int t2 = g / 40;
    int rr = t2 % 31;
    int bzi = t2 / 31;
    int b = bzi & 7;
    unsigned short* z = (bzi >> 3) ? z2 : z1;
    int l, j, off5;
    if (rr < 16)      { l = 6;  j = rr;      off5 = 0; }
    else if (rr < 24) { l = 7;  j = rr - 16; off5 = 16; }
    else if (rr < 28) { l = 8;  j = rr - 24; off5 = 24; }
    else if (rr < 30) { l = 9;  j = rr - 28; off5 = 28; }
    else              { l = 10; j = rr - 30; off5 = 30; }
    int len = L5LEN[b * 32 + off5 + j];
    const int* st = SET5 + b * 160 + (l - 6) * 32 + (j << (l - 5));
    const unsigned short* src = z + (size_t)2560 * (2048 - 64) + (size_t)b * 32 * D_DIM;
    int cc = c * 8;
    bf16x8_t mx = *(const bf16x8_t*)(src + (size_t)st[0] * D_DIM + cc);
    for (int e = 1; e < len; ++e) {
      bf16x8_t a = *(const bf16x8_t*)(src + (size_t)st[e] * D_DIM + cc);
#pragma unroll
      for (int q = 0; q < 8; ++q)
        mx[q] = (bf2f((unsigned short)mx[q]) >= bf2f((unsigned short)a[q])) ? mx[q] : a[q];
    }
    size_t zo = (size_t)2560 * (2048 - (2048 >> l));
    int Tl = 1024 >> l;
    *(bf16x8_t*)(z + zo + ((size_t)b * Tl + j) * D_DIM + cc) = mx;
  } else {
    // ========== levels 1..5 instance ==========
    int iw = 1024 + (bx - 486) * 4 + (tid >> 6);
    if (iw < 2016) {
      int l = 1;
      while (iw >= tab.instStart[l + 1]) ++l;
      int t = iw - tab.instStart[l];
      float lsum = inst_wave(z1 + tab.zoff[l], z2 + tab.zoff[l], tab.T[l], t,
                             tid & 63);
      if ((tid & 63) == 0) wsInst[iw] = lsum * tab.scale[l];
    }
  }
}

// ---------------- final: combine + tiny temporal (6-9) + inst 6-10 ----------
__global__ __launch_bounds__(256) void final_kernel(
    const unsigned short* __restrict__ z1, const unsigned short* __restrict__ z2,
    const float* __restrict__ wsm, const float* __restrict__ wss,
    const float* __restrict__ wpos,
    const float* __restrict__ wsInst, float* __restrict__ out, Tab tab,
    int nc) {
  int bx = blockIdx.x;
  int tid = threadIdx.x;

  if (bx < nc) {
    int g = bx * 256 + tid;
    float loss = 0.f;
    if (g < tab.totr) {
      int l = 0;
      while (g >= tab.rstart[l + 1]) ++l;
      int row = g - tab.rstart[l];
      int T = tab.T[l], N = 2 * T, S = tab.S[l];
      int b = row / N, r = row % N;
      const float* wm = wsm + tab.wsoff[l];
      const float* wv = wss + tab.wsoff[l];
      float m = NEGINF;
      for (int s = 0; s < S; ++s) m = fmaxf(m, wm[(b * S + s) * N + r]);
      float sv = 0.f;
      for (int s = 0; s < S; ++s) {
        int idx = (b * S + s) * N + r;
        sv += wv[idx] * __expf(wm[idx] - m);
      }
      float dot = wpos[tab.rstart[l] + b * N + r];
      loss = (m + logf(sv) - dot) * tab.scale[l];
    } else if (g < tab.totr + 2016) {
      loss = wsInst[g - tab.totr];
    }
    float v = loss;
#pragma unroll
    for (int o = 1; o < 64; o <<= 1) v += __shfl_xor(v, o);
    __shared__ float part[4];
    int w = tid >> 6;
    if ((tid & 63) == 0) part[w] = v;
    __syncthreads();
    if (tid == 0)
      atomicAdd(out, part[0] + part[1] + part[2] + part[3]);
  } else if (bx < nc + 8) {
    // ---- tiny temporal levels 6..9: one wave per (b, l), 32x32 MFMA ----
    int widx = (bx - nc) * 4 + (tid >> 6);
    int l = 6 + (widx >> 3), b = widx & 7;
    int T = tab.T[l], N = 2 * T;
    const unsigned short* zz1 = z1 + tab.zoff[l];
    const unsigned short* zz2 = z2 + tab.zoff[l];
    int lane = tid & 63;
    int col = lane & 31, h = lane >> 5;
    int rl = (col < N) ? col : 0;
    const unsigned short* rowp = (rl < T)
        ? zz1 + ((size_t)b * T + rl) * D_DIM
        : zz2 + ((size_t)b * T + (rl - T)) * D_DIM;
    rowp += h * 8;
    f32x16_t acc = (f32x16_t)(0.f);
#pragma unroll
    for (int m2 = 0; m2 < 20; ++m2) {
      bf16x8_t a = *(const bf16x8_t*)(rowp + m2 * 16);
      acc = __builtin_amdgcn_mfma_f32_32x32x16_bf16(a, a, acc, 0, 0, 0);
    }
    float lsum = 0.f;
#pragma unroll
    for (int rg = 0; rg < 16; ++rg) {
      int row = (rg & 3) + 8 * (rg >> 2) + 4 * h;
      float x = acc[rg];
      float xm = (col < N && row < N && col != row) ? x : NEGINF;
      float m = xm;
#pragma unroll
      for (int o = 1; o < 32; o <<= 1) m = fmaxf(m, __shfl_xor(m, o));
      float s = __expf(xm - m);
#pragma unroll
      for (int o = 1; o < 32; o <<= 1) s += __shfl_xor(s, o);
      int pos = (row < T) ? row + T : row - T;
      if (row < N && col == pos) lsum += m + __logf(s) - x;
    }
#pragma unroll
    for (int o = 1; o < 64; o <<= 1) lsum += __shfl_xor(lsum, o);
    if (lane == 0) atomicAdd(out, lsum * tab.scale[l]);
  } else {
    // ---- instance levels 6..10: one wave per t, direct atomic ----
    int widx = (bx - nc - 8) * 4 + (tid >> 6);
    if (widx < 31) {
      int iw = 2016 + widx;
      int l = 6;
      while (iw >= tab.instStart[l + 1]) ++l;
      int t = iw - tab.instStart[l];
      float lsum = inst_wave(z1 + tab.zoff[l], z2 + tab.zoff[l], tab.T[l], t,
                             tid & 63);
      if ((tid & 63) == 0) atomicAdd(out, lsum * tab.scale[l]);
    }
  }
}

extern "C" void kernel_launch(void* const* d_in, const int* in_sizes, int n_in,
                              void* d_out, int out_size, void* d_ws, size_t ws_size,
                              hipStream_t stream) {
  const float* z1_in = (const float*)d_in[0];
  const float* z2_in = (const float*)d_in[1];
  const int* time_in = (const int*)d_in[2];
  float* out = (float*)d_out;

  // ---- level tables ----
  Tab tab;
  int zo = 0, wso = 0, ts = 0, is = 0, rs = 0;
  for (int l = 0; l < 11; ++l) {
    int T = 1024 >> l, N = 2 * T;
    int S = (N >= 128) ? N / 128 : 1;
    tab.T[l] = T;
    tab.S[l] = S;
    tab.zoff[l] = zo;
    tab.scale[l] = 1.0f / (352.0f * (float)T);  // 0.5/(2*B*T)/11
    tab.tileStart[l] = ts;
    tab.instStart[l] = is;
    tab.wsoff[l] = (T > 1) ? wso : 0;
    tab.rstart[l] = rs;
    if (T > 1) {
      ts += 8 * ((S * (S + 1)) >> 1);
      wso += 8 * S * N;
      if (l <= 5) rs += 8 * N;   // combine covers temporal rows of levels 0..5
    }
    is += T;
    zo += 8 * T * D_DIM;
  }
  tab.tileStart[11] = ts;
  tab.instStart[11] = is;
  for (int l = 6; l <= 11; ++l) tab.rstart[l] = rs;
  tab.totTemp = ts;
  tab.totInst = is;
  tab.totr = rs;

  // ---- workspace carve ----
  char* w = (char*)d_ws;
  unsigned short* z1s = (unsigned short*)w; w += (size_t)zo * 2;
  unsigned short* z2s = (unsigned short*)w; w += (size_t)zo * 2;
  float* wsm = (float*)w; w += (size_t)wso * sizeof(float);
  float* wss = (float*)w; w += (size_t)wso * sizeof(float);
  float* wpos = (float*)w; w += (size_t)rs * sizeof(float);
  float* wsInst = (float*)w; w += (size_t)is * sizeof(float);
  int* SET0 = (int*)w; w += (size_t)8 * 5120 * sizeof(int);
  int* L0LEN = (int*)w; w += (size_t)8 * 992 * sizeof(int);
  int* SET5 = (int*)w; w += (size_t)8 * 160 * sizeof(int);
  int* L5LEN = (int*)w; w += (size_t)8 * 32 * sizeof(int);

  int n0 = 8 * 1024 * D_DIM;
  convert_kernel<<<2048, 256, 0, stream>>>(z1_in, z2_in, z1s, z2s, n0 / 4,
                                           out, out_size);
  work0_kernel<<<8 + 1088 + 256, 256, 0, stream>>>(
      time_in, z1s, z2s, wsm, wss, wpos, wsInst, SET0, L0LEN, SET5, L5LEN);
  mat1_kernel<<<2480, 256, 0, stream>>>(z1s, z2s, SET0, L0LEN);
  work45_kernel<<<408 + 78 + 248, 256, 0, stream>>>(
      z1s, z2s, SET5, L5LEN, wsm, wss, wpos, wsInst, tab);
  int nc = (tab.totr + 2016 + 255) / 256;
  final_kernel<<<nc + 16, 256, 0, stream>>>(z1s, z2s, wsm, wss, wpos, wsInst,
                                            out, tab, nc);
}